// Round 1
// baseline (1295.052 us; speedup 1.0000x reference)
//
#include <hip/hip_runtime.h>
#include <math.h>

#define NV 64
#define ND 64
#define NTOK 8192
#define LN_EPS 1e-5f

__device__ __forceinline__ float elu_f(float x)  { return x > 0.f ? x : expm1f(x); }
__device__ __forceinline__ float sigm_f(float x) { return 1.f / (1.f + expf(-x)); }

// ---------------- Stage 1: per-variable GRN + LayerNorm -> stacked[tok][v][d]
// grid: (128 token-tiles, 64 variables), block: 256
__global__ __launch_bounds__(256) void vsn_stage1(
    const float* __restrict__ x,
    const float* __restrict__ W1, const float* __restrict__ b1,
    const float* __restrict__ W2, const float* __restrict__ b2,
    const float* __restrict__ Wg, const float* __restrict__ bg,
    const float* __restrict__ Wsk, const float* __restrict__ bsk,
    const float* __restrict__ gamma, const float* __restrict__ beta,
    float* __restrict__ stacked)
{
    const int t = threadIdx.x;
    const int tile0 = blockIdx.x * 64;   // token base
    const int v = blockIdx.y;

    __shared__ __align__(16) float xs[64];
    __shared__ __align__(16) float buf[64][64];    // h1 then h2
    __shared__ __align__(16) float sbuf[64][68];   // pre-LN (padded: stride 68)

    if (t < 64) xs[t] = x[(size_t)(tile0 + t) * NV + v];
    __syncthreads();

    // h1[tt][d] = elu(x*W1 + b1)
    #pragma unroll
    for (int i = 0; i < 16; ++i) {
        int idx = i * 256 + t;
        int tt = idx >> 6, d = idx & 63;
        buf[tt][d] = elu_f(xs[tt] * W1[v * 64 + d] + b1[v * 64 + d]);
    }
    __syncthreads();

    const int e  = t & 63;
    const int g0 = t >> 6;   // == wave id

    // ---- h2 = h1 @ W2_v + b2  (weight column in registers, h1 via LDS broadcast)
    float w[64];
    {
        const float* W2v = W2 + (size_t)v * 4096;
        #pragma unroll
        for (int d = 0; d < 64; ++d) w[d] = W2v[d * 64 + e];   // coalesced over e
    }
    float acc[16];
    {
        float b2v = b2[v * 64 + e];
        #pragma unroll
        for (int i = 0; i < 16; ++i) acc[i] = b2v;
    }
    #pragma unroll
    for (int i = 0; i < 16; ++i) {
        int tt = g0 * 16 + i;
        #pragma unroll
        for (int d4 = 0; d4 < 16; ++d4) {
            float4 f = *(const float4*)&buf[tt][d4 * 4];       // wave-uniform broadcast
            acc[i] += f.x * w[4*d4] + f.y * w[4*d4+1] + f.z * w[4*d4+2] + f.w * w[4*d4+3];
        }
    }
    __syncthreads();   // everyone done reading h1
    #pragma unroll
    for (int i = 0; i < 16; ++i) buf[g0 * 16 + i][e] = acc[i];  // h2 into LDS
    __syncthreads();

    // ---- g = sigmoid(h2 @ Wg_v + bg); s = x*Wsk + bsk + g*h2
    {
        const float* Wgv = Wg + (size_t)v * 4096;
        #pragma unroll
        for (int d = 0; d < 64; ++d) w[d] = Wgv[d * 64 + e];
    }
    float gacc[16];
    {
        float bgv = bg[v * 64 + e];
        #pragma unroll
        for (int i = 0; i < 16; ++i) gacc[i] = bgv;
    }
    #pragma unroll
    for (int i = 0; i < 16; ++i) {
        int tt = g0 * 16 + i;
        #pragma unroll
        for (int d4 = 0; d4 < 16; ++d4) {
            float4 f = *(const float4*)&buf[tt][d4 * 4];
            gacc[i] += f.x * w[4*d4] + f.y * w[4*d4+1] + f.z * w[4*d4+2] + f.w * w[4*d4+3];
        }
    }
    {
        float wskv = Wsk[v * 64 + e], bskv = bsk[v * 64 + e];
        #pragma unroll
        for (int i = 0; i < 16; ++i) {
            int tt = g0 * 16 + i;
            float h2v = buf[tt][e];
            float g = sigm_f(gacc[i]);
            sbuf[tt][e] = xs[tt] * wskv + bskv + g * h2v;
        }
    }
    __syncthreads();

    // ---- LayerNorm over d per (token,variable) row; 4 lanes per row
    {
        int row = t >> 2, l = t & 3;
        float sum = 0.f, sq = 0.f;
        #pragma unroll
        for (int i = 0; i < 16; ++i) {
            float s0 = sbuf[row][l + 4 * i];
            sum += s0; sq += s0 * s0;
        }
        sum += __shfl_xor(sum, 1); sum += __shfl_xor(sum, 2);
        sq  += __shfl_xor(sq, 1);  sq  += __shfl_xor(sq, 2);
        float mu  = sum * 0.015625f;
        float var = sq * 0.015625f - mu * mu;
        float rs  = rsqrtf(var + LN_EPS);
        size_t base = (size_t)(tile0 + row) * 4096 + (size_t)v * 64;
        #pragma unroll
        for (int i = 0; i < 16; ++i) {
            int ee = l + 4 * i;
            stacked[base + ee] = (sbuf[row][ee] - mu) * rs * gamma[v * 64 + ee] + beta[v * 64 + ee];
        }
    }
}

// ---------------- Stage 2: weight-net GRN + softmax + weighted sum
// grid: 512 blocks x 16 tokens, block: 256
__global__ __launch_bounds__(256) void vsn_stage2(
    const float* __restrict__ stacked,
    const float* __restrict__ Wn1, const float* __restrict__ bn1,
    const float* __restrict__ Wn2, const float* __restrict__ bn2,
    const float* __restrict__ Wng, const float* __restrict__ bng,
    const float* __restrict__ Wns, const float* __restrict__ bns,
    const float* __restrict__ ngamma, const float* __restrict__ nbeta,
    float* __restrict__ out)
{
    const int t = threadIdx.x;
    const int tok0 = blockIdx.x * 16;

    __shared__ __align__(16) float flat_s[16][256];
    __shared__ float red1[16][4][64];
    __shared__ float red2[16][4][64];
    __shared__ __align__(16) float hw1_s[16][64];
    __shared__ float skw_s[16][64];
    __shared__ __align__(16) float hw2_s[16][64];
    __shared__ float s2_s[16][64];
    __shared__ float w_s[16][64];

    const int j  = t & 63;
    const int gi = t >> 6;   // wave id: k-range quarter

    float acc1[16], accS[16];
    #pragma unroll
    for (int tt = 0; tt < 16; ++tt) { acc1[tt] = 0.f; accS[tt] = 0.f; }

    // ---- flat @ Wn1 (->hw1 partial) and flat @ Wns (->skw partial), chunked over k
    for (int c = 0; c < 16; ++c) {
        #pragma unroll
        for (int ii = 0; ii < 16; ++ii) {
            int lidx = ii * 256 + t;
            int tt = lidx >> 8, kk = lidx & 255;
            flat_s[tt][kk] = stacked[(size_t)(tok0 + tt) * 4096 + c * 256 + kk];
        }
        __syncthreads();
        const float* Wn1c = Wn1 + (size_t)(c * 256 + gi * 64) * 64 + j;
        const float* Wnsc = Wns + (size_t)(c * 256 + gi * 64) * 64 + j;
        #pragma unroll
        for (int q4 = 0; q4 < 16; ++q4) {
            float w1a = Wn1c[(q4*4+0)*64], w1b = Wn1c[(q4*4+1)*64];
            float w1c_ = Wn1c[(q4*4+2)*64], w1d = Wn1c[(q4*4+3)*64];
            float wsa = Wnsc[(q4*4+0)*64], wsb = Wnsc[(q4*4+1)*64];
            float wsc = Wnsc[(q4*4+2)*64], wsd = Wnsc[(q4*4+3)*64];
            #pragma unroll
            for (int tt = 0; tt < 16; ++tt) {
                float4 f = *(const float4*)&flat_s[tt][gi * 64 + q4 * 4];  // wave-uniform
                acc1[tt] += f.x * w1a + f.y * w1b + f.z * w1c_ + f.w * w1d;
                accS[tt] += f.x * wsa + f.y * wsb + f.z * wsc + f.w * wsd;
            }
        }
        __syncthreads();
    }
    #pragma unroll
    for (int tt = 0; tt < 16; ++tt) { red1[tt][gi][j] = acc1[tt]; red2[tt][gi][j] = accS[tt]; }
    __syncthreads();

    // ---- reduce quarters: hw1 = elu(.+bn1), skw = .+bns
    #pragma unroll
    for (int i = 0; i < 4; ++i) {
        int oidx = i * 256 + t;
        int tt = oidx >> 6, jj = oidx & 63;
        float s1 = red1[tt][0][jj] + red1[tt][1][jj] + red1[tt][2][jj] + red1[tt][3][jj];
        float ss = red2[tt][0][jj] + red2[tt][1][jj] + red2[tt][2][jj] + red2[tt][3][jj];
        hw1_s[tt][jj] = elu_f(s1 + bn1[jj]);
        skw_s[tt][jj] = ss + bns[jj];
    }
    __syncthreads();

    // ---- hw2 = hw1 @ Wn2 + bn2
    #pragma unroll
    for (int i = 0; i < 4; ++i) {
        int oidx = i * 256 + t;
        int tt = oidx >> 6, jj = oidx & 63;
        float acc = bn2[jj];
        #pragma unroll
        for (int k4 = 0; k4 < 16; ++k4) {
            float4 h = *(const float4*)&hw1_s[tt][k4 * 4];
            acc += h.x * Wn2[(k4*4+0)*64+jj] + h.y * Wn2[(k4*4+1)*64+jj]
                 + h.z * Wn2[(k4*4+2)*64+jj] + h.w * Wn2[(k4*4+3)*64+jj];
        }
        hw2_s[tt][jj] = acc;
    }
    __syncthreads();

    // ---- gw = sigmoid(hw2 @ Wng + bng); s2 = skw + gw*hw2
    #pragma unroll
    for (int i = 0; i < 4; ++i) {
        int oidx = i * 256 + t;
        int tt = oidx >> 6, vv = oidx & 63;
        float acc = bng[vv];
        #pragma unroll
        for (int k4 = 0; k4 < 16; ++k4) {
            float4 h = *(const float4*)&hw2_s[tt][k4 * 4];
            acc += h.x * Wng[(k4*4+0)*64+vv] + h.y * Wng[(k4*4+1)*64+vv]
                 + h.z * Wng[(k4*4+2)*64+vv] + h.w * Wng[(k4*4+3)*64+vv];
        }
        float gw = sigm_f(acc);
        s2_s[tt][vv] = skw_s[tt][vv] + gw * hw2_s[tt][vv];
    }
    __syncthreads();

    // ---- LN over v + softmax; 16 lanes per token
    {
        int tt = t >> 4, l = t & 15;
        float z[4]; float sum = 0.f, sq = 0.f;
        #pragma unroll
        for (int i = 0; i < 4; ++i) { z[i] = s2_s[tt][l + 16 * i]; sum += z[i]; sq += z[i] * z[i]; }
        #pragma unroll
        for (int m = 1; m < 16; m <<= 1) { sum += __shfl_xor(sum, m); sq += __shfl_xor(sq, m); }
        float mu  = sum * 0.015625f;
        float var = sq * 0.015625f - mu * mu;
        float rs  = rsqrtf(var + LN_EPS);
        float ln[4]; float mx = -1e30f;
        #pragma unroll
        for (int i = 0; i < 4; ++i) {
            ln[i] = (z[i] - mu) * rs * ngamma[l + 16 * i] + nbeta[l + 16 * i];
            mx = fmaxf(mx, ln[i]);
        }
        #pragma unroll
        for (int m = 1; m < 16; m <<= 1) mx = fmaxf(mx, __shfl_xor(mx, m));
        float es = 0.f; float ev[4];
        #pragma unroll
        for (int i = 0; i < 4; ++i) { ev[i] = expf(ln[i] - mx); es += ev[i]; }
        #pragma unroll
        for (int m = 1; m < 16; m <<= 1) es += __shfl_xor(es, m);
        float inv = 1.f / es;
        #pragma unroll
        for (int i = 0; i < 4; ++i) w_s[tt][l + 16 * i] = ev[i] * inv;
    }
    __syncthreads();

    // ---- out[tok][d] = sum_v w[v] * stacked[tok][v][d]
    {
        int d = t & 63, g = t >> 6;
        #pragma unroll
        for (int i = 0; i < 4; ++i) {
            int tt = g * 4 + i;
            const float* sp = stacked + (size_t)(tok0 + tt) * 4096 + d;
            float acc = 0.f;
            #pragma unroll
            for (int vv = 0; vv < 64; ++vv) acc += w_s[tt][vv] * sp[vv * 64];
            out[(size_t)(tok0 + tt) * 64 + d] = acc;
        }
    }
}

extern "C" void kernel_launch(void* const* d_in, const int* in_sizes, int n_in,
                              void* d_out, int out_size, void* d_ws, size_t ws_size,
                              hipStream_t stream) {
    const float* x     = (const float*)d_in[0];
    const float* W1    = (const float*)d_in[1];
    const float* b1    = (const float*)d_in[2];
    const float* W2    = (const float*)d_in[3];
    const float* b2    = (const float*)d_in[4];
    const float* Wg    = (const float*)d_in[5];
    const float* bg    = (const float*)d_in[6];
    const float* Wsk   = (const float*)d_in[7];
    const float* bsk   = (const float*)d_in[8];
    const float* gamma = (const float*)d_in[9];
    const float* beta  = (const float*)d_in[10];
    const float* Wn1   = (const float*)d_in[11];
    const float* bn1   = (const float*)d_in[12];
    const float* Wn2   = (const float*)d_in[13];
    const float* bn2   = (const float*)d_in[14];
    const float* Wng   = (const float*)d_in[15];
    const float* bng   = (const float*)d_in[16];
    const float* Wns   = (const float*)d_in[17];
    const float* bns   = (const float*)d_in[18];
    const float* ngam  = (const float*)d_in[19];
    const float* nbet  = (const float*)d_in[20];

    float* stacked = (float*)d_ws;   // 8192*4096*4 B = 128 MiB
    float* outp    = (float*)d_out;

    vsn_stage1<<<dim3(NTOK / 64, NV), 256, 0, stream>>>(
        x, W1, b1, W2, b2, Wg, bg, Wsk, bsk, gamma, beta, stacked);
    vsn_stage2<<<dim3(NTOK / 16), 256, 0, stream>>>(
        stacked, Wn1, bn1, Wn2, bn2, Wng, bng, Wns, bns, ngam, nbet, outp);
}

// Round 2
// 770.681 us; speedup vs baseline: 1.6804x; 1.6804x over previous
//
#include <hip/hip_runtime.h>
#include <math.h>

#define NV 64
#define ND 64
#define NTOK 8192
#define LN_EPS 1e-5f
#define KSPLIT 4
#define KRANGE 1024   // 4096 / KSPLIT
#define KC 32

__device__ __forceinline__ float elu_f(float x)  { return x > 0.f ? x : expm1f(x); }
__device__ __forceinline__ float sigm_f(float x) { return 1.f / (1.f + expf(-x)); }
__device__ __forceinline__ void f4st(float* d, float4 v){ d[0]=v.x; d[1]=v.y; d[2]=v.z; d[3]=v.w; }

// ---------------- Stage 1: per-variable GRN + LayerNorm -> stacked[tok][v][d]
// grid: (128 token-tiles, 64 variables), block 256.
// Activations live TRANSPOSED in LDS (bufT[k][token]) so each ds_read_b128
// (4 tokens) + one global float4 of weights (L1) feeds 16 FMAs.
__global__ __launch_bounds__(256) void vsn_stage1(
    const float* __restrict__ x,
    const float* __restrict__ W1, const float* __restrict__ b1,
    const float* __restrict__ W2, const float* __restrict__ b2,
    const float* __restrict__ Wg, const float* __restrict__ bg,
    const float* __restrict__ Wsk, const float* __restrict__ bsk,
    const float* __restrict__ gamma, const float* __restrict__ beta,
    float* __restrict__ stacked)
{
    const int t = threadIdx.x;
    const int tile0 = blockIdx.x * 64;
    const int v = blockIdx.y;
    const int nq = t & 15, tq = t >> 4;
    const int e0 = nq * 4, tokl = tq * 4;

    __shared__ __align__(16) float xs[64];
    __shared__ __align__(16) float bufT[64][68];   // [k][token], h1 then h2
    __shared__ __align__(16) float sbuf[64][68];   // [token][e] pre-LN

    if (t < 64) xs[t] = x[(size_t)(tile0 + t) * NV + v];
    __syncthreads();

    float xtok[4];
    f4st(xtok, *(const float4*)&xs[tokl]);

    // ---- h1 = elu(x*W1 + b1), stored transposed
    {
        float w1[4], bb[4];
        f4st(w1, *(const float4*)(W1 + v * 64 + e0));
        f4st(bb, *(const float4*)(b1 + v * 64 + e0));
        #pragma unroll
        for (int j = 0; j < 4; ++j) {
            float4 o;
            o.x = elu_f(xtok[0] * w1[j] + bb[j]);
            o.y = elu_f(xtok[1] * w1[j] + bb[j]);
            o.z = elu_f(xtok[2] * w1[j] + bb[j]);
            o.w = elu_f(xtok[3] * w1[j] + bb[j]);
            *(float4*)&bufT[e0 + j][tokl] = o;
        }
    }

    // ---- GEMM1: h2 = h1 @ W2_v + b2  (4tok x 4col register tile)
    float h2r[4][4];
    {
        float bb[4]; f4st(bb, *(const float4*)(b2 + v * 64 + e0));
        #pragma unroll
        for (int i = 0; i < 4; ++i)
            #pragma unroll
            for (int j = 0; j < 4; ++j) h2r[i][j] = bb[j];
    }
    __syncthreads();
    {
        const float* Wv = W2 + (size_t)v * 4096;
        #pragma unroll 4
        for (int k = 0; k < 64; ++k) {
            float a[4], w[4];
            f4st(a, *(const float4*)&bufT[k][tokl]);
            f4st(w, *(const float4*)(Wv + k * 64 + e0));
            #pragma unroll
            for (int i = 0; i < 4; ++i)
                #pragma unroll
                for (int j = 0; j < 4; ++j) h2r[i][j] += a[i] * w[j];
        }
    }
    __syncthreads();   // all reads of h1 done
    #pragma unroll
    for (int j = 0; j < 4; ++j) {
        float4 o = make_float4(h2r[0][j], h2r[1][j], h2r[2][j], h2r[3][j]);
        *(float4*)&bufT[e0 + j][tokl] = o;   // h2 transposed
    }

    // ---- GEMM2: g = sigmoid(h2 @ Wg_v + bg)
    float ga[4][4];
    {
        float bb[4]; f4st(bb, *(const float4*)(bg + v * 64 + e0));
        #pragma unroll
        for (int i = 0; i < 4; ++i)
            #pragma unroll
            for (int j = 0; j < 4; ++j) ga[i][j] = bb[j];
    }
    __syncthreads();   // h2T visible
    {
        const float* Wv = Wg + (size_t)v * 4096;
        #pragma unroll 4
        for (int k = 0; k < 64; ++k) {
            float a[4], w[4];
            f4st(a, *(const float4*)&bufT[k][tokl]);
            f4st(w, *(const float4*)(Wv + k * 64 + e0));
            #pragma unroll
            for (int i = 0; i < 4; ++i)
                #pragma unroll
                for (int j = 0; j < 4; ++j) ga[i][j] += a[i] * w[j];
        }
    }

    // ---- s = x*Wsk + bsk + g*h2  -> sbuf[token][e]
    {
        float wsk4[4], bsk4[4];
        f4st(wsk4, *(const float4*)(Wsk + v * 64 + e0));
        f4st(bsk4, *(const float4*)(bsk + v * 64 + e0));
        #pragma unroll
        for (int i = 0; i < 4; ++i) {
            float4 o;
            o.x = xtok[i] * wsk4[0] + bsk4[0] + sigm_f(ga[i][0]) * h2r[i][0];
            o.y = xtok[i] * wsk4[1] + bsk4[1] + sigm_f(ga[i][1]) * h2r[i][1];
            o.z = xtok[i] * wsk4[2] + bsk4[2] + sigm_f(ga[i][2]) * h2r[i][2];
            o.w = xtok[i] * wsk4[3] + bsk4[3] + sigm_f(ga[i][3]) * h2r[i][3];
            *(float4*)&sbuf[tokl + i][e0] = o;
        }
    }
    __syncthreads();

    // ---- LayerNorm over d; 4 lanes per (token,variable) row  [round-1 verified]
    {
        int row = t >> 2, l = t & 3;
        float sum = 0.f, sq = 0.f;
        #pragma unroll
        for (int i = 0; i < 16; ++i) {
            float s0 = sbuf[row][l + 4 * i];
            sum += s0; sq += s0 * s0;
        }
        sum += __shfl_xor(sum, 1); sum += __shfl_xor(sum, 2);
        sq  += __shfl_xor(sq, 1);  sq  += __shfl_xor(sq, 2);
        float mu  = sum * 0.015625f;
        float var = sq * 0.015625f - mu * mu;
        float rs  = rsqrtf(var + LN_EPS);
        size_t base = (size_t)(tile0 + row) * 4096 + (size_t)v * 64;
        #pragma unroll
        for (int i = 0; i < 16; ++i) {
            int ee = l + 4 * i;
            stacked[base + ee] = (sbuf[row][ee] - mu) * rs * gamma[v * 64 + ee] + beta[v * 64 + ee];
        }
    }
}

// ---------------- Stage 2a: C[8192x128] = flat @ [Wn1 | Wns], K-split into 4 partials
// grid (128 M-tiles of 64 tokens, 4 K-splits), block 128 threads.
// 8tok x 8n register tile: 2 ds_read_b128 + 2 global float4 per 64 FMAs.
__global__ __launch_bounds__(128) void vsn_stage2a(
    const float* __restrict__ stacked,
    const float* __restrict__ Wn1, const float* __restrict__ Wns,
    float* __restrict__ part)
{
    const int t = threadIdx.x;
    const int tok0 = blockIdx.x * 64;
    const int s = blockIdx.y;
    const int k0 = s * KRANGE;
    const int nq = t & 15, tq = t >> 4;       // tq 0..7 -> 8 tokens, nq 0..15 -> 8 cols
    const int tokl = tq * 8;
    const int nc = (nq & 7) * 8;
    const float* Wp = (nq < 8) ? Wn1 : Wns;

    __shared__ __align__(16) float flatT[KC][68];   // [k][token]

    float acc[8][8];
    #pragma unroll
    for (int i = 0; i < 8; ++i)
        #pragma unroll
        for (int j = 0; j < 8; ++j) acc[i][j] = 0.f;

    // register-prefetch staging: 4 float4 per thread per chunk
    float4 pre[4];
    #pragma unroll
    for (int q = 0; q < 4; ++q) {
        int fi = q * 128 + t, tok = fi >> 3, kk4 = fi & 7;
        pre[q] = *(const float4*)(stacked + (size_t)(tok0 + tok) * 4096 + k0 + kk4 * 4);
    }

    for (int c = 0; c < KRANGE / KC; ++c) {
        #pragma unroll
        for (int q = 0; q < 4; ++q) {
            int fi = q * 128 + t, tok = fi >> 3, kk4 = fi & 7;
            float tmp[4]; f4st(tmp, pre[q]);
            #pragma unroll
            for (int w = 0; w < 4; ++w) flatT[kk4 * 4 + w][tok] = tmp[w];
        }
        __syncthreads();
        if (c + 1 < KRANGE / KC) {
            #pragma unroll
            for (int q = 0; q < 4; ++q) {
                int fi = q * 128 + t, tok = fi >> 3, kk4 = fi & 7;
                pre[q] = *(const float4*)(stacked + (size_t)(tok0 + tok) * 4096
                                          + k0 + (c + 1) * KC + kk4 * 4);
            }
        }
        const float* wrow = Wp + (size_t)(k0 + c * KC) * 64 + nc;
        #pragma unroll 2
        for (int k = 0; k < KC; ++k) {
            float a[8], w[8];
            f4st(a,     *(const float4*)&flatT[k][tokl]);
            f4st(a + 4, *(const float4*)&flatT[k][tokl + 4]);
            f4st(w,     *(const float4*)(wrow + k * 64));
            f4st(w + 4, *(const float4*)(wrow + k * 64 + 4));
            #pragma unroll
            for (int i = 0; i < 8; ++i)
                #pragma unroll
                for (int j = 0; j < 8; ++j) acc[i][j] += a[i] * w[j];
        }
        __syncthreads();
    }

    #pragma unroll
    for (int i = 0; i < 8; ++i) {
        size_t base = ((size_t)s * NTOK + (tok0 + tokl + i)) * 128 + nq * 8;
        *(float4*)(part + base)     = make_float4(acc[i][0], acc[i][1], acc[i][2], acc[i][3]);
        *(float4*)(part + base + 4) = make_float4(acc[i][4], acc[i][5], acc[i][6], acc[i][7]);
    }
}

// ---------------- Stage 2b: reduce partials, weight-net tail, softmax, weighted sum
// grid 512 x 16 tokens, block 256.
__global__ __launch_bounds__(256) void vsn_stage2b(
    const float* __restrict__ stacked, const float* __restrict__ part,
    const float* __restrict__ bn1,
    const float* __restrict__ Wn2, const float* __restrict__ bn2,
    const float* __restrict__ Wng, const float* __restrict__ bng,
    const float* __restrict__ bns,
    const float* __restrict__ ngamma, const float* __restrict__ nbeta,
    float* __restrict__ out)
{
    const int t = threadIdx.x;
    const int tok0 = blockIdx.x * 16;

    __shared__ __align__(16) float hw1_s[16][64];
    __shared__ float skw_s[16][64];
    __shared__ __align__(16) float hw2_s[16][64];
    __shared__ float s2_s[16][64];
    __shared__ float w_s[16][64];

    // ---- hw1 = elu(sum_s part + bn1), skw = sum_s part + bns
    #pragma unroll
    for (int i = 0; i < 4; ++i) {
        int oidx = i * 256 + t;
        int tt = oidx >> 6, jj = oidx & 63;
        size_t rb = (size_t)(tok0 + tt) * 128;
        float p1 = 0.f, ps = 0.f;
        #pragma unroll
        for (int s = 0; s < KSPLIT; ++s) {
            p1 += part[(size_t)s * NTOK * 128 + rb + jj];
            ps += part[(size_t)s * NTOK * 128 + rb + 64 + jj];
        }
        hw1_s[tt][jj] = elu_f(p1 + bn1[jj]);
        skw_s[tt][jj] = ps + bns[jj];
    }
    __syncthreads();

    // ---- hw2 = hw1 @ Wn2 + bn2
    #pragma unroll
    for (int i = 0; i < 4; ++i) {
        int oidx = i * 256 + t;
        int tt = oidx >> 6, jj = oidx & 63;
        float acc = bn2[jj];
        #pragma unroll
        for (int k4 = 0; k4 < 16; ++k4) {
            float4 h = *(const float4*)&hw1_s[tt][k4 * 4];
            acc += h.x * Wn2[(k4*4+0)*64+jj] + h.y * Wn2[(k4*4+1)*64+jj]
                 + h.z * Wn2[(k4*4+2)*64+jj] + h.w * Wn2[(k4*4+3)*64+jj];
        }
        hw2_s[tt][jj] = acc;
    }
    __syncthreads();

    // ---- gw = sigmoid(hw2 @ Wng + bng); s2 = skw + gw*hw2
    #pragma unroll
    for (int i = 0; i < 4; ++i) {
        int oidx = i * 256 + t;
        int tt = oidx >> 6, vv = oidx & 63;
        float acc = bng[vv];
        #pragma unroll
        for (int k4 = 0; k4 < 16; ++k4) {
            float4 h = *(const float4*)&hw2_s[tt][k4 * 4];
            acc += h.x * Wng[(k4*4+0)*64+vv] + h.y * Wng[(k4*4+1)*64+vv]
                 + h.z * Wng[(k4*4+2)*64+vv] + h.w * Wng[(k4*4+3)*64+vv];
        }
        float gw = sigm_f(acc);
        s2_s[tt][vv] = skw_s[tt][vv] + gw * hw2_s[tt][vv];
    }
    __syncthreads();

    // ---- LN over v + softmax; 16 lanes per token  [round-1 verified]
    {
        int tt = t >> 4, l = t & 15;
        float z[4]; float sum = 0.f, sq = 0.f;
        #pragma unroll
        for (int i = 0; i < 4; ++i) { z[i] = s2_s[tt][l + 16 * i]; sum += z[i]; sq += z[i] * z[i]; }
        #pragma unroll
        for (int m = 1; m < 16; m <<= 1) { sum += __shfl_xor(sum, m); sq += __shfl_xor(sq, m); }
        float mu  = sum * 0.015625f;
        float var = sq * 0.015625f - mu * mu;
        float rs  = rsqrtf(var + LN_EPS);
        float ln[4]; float mx = -1e30f;
        #pragma unroll
        for (int i = 0; i < 4; ++i) {
            ln[i] = (z[i] - mu) * rs * ngamma[l + 16 * i] + nbeta[l + 16 * i];
            mx = fmaxf(mx, ln[i]);
        }
        #pragma unroll
        for (int m = 1; m < 16; m <<= 1) mx = fmaxf(mx, __shfl_xor(mx, m));
        float es = 0.f; float ev[4];
        #pragma unroll
        for (int i = 0; i < 4; ++i) { ev[i] = expf(ln[i] - mx); es += ev[i]; }
        #pragma unroll
        for (int m = 1; m < 16; m <<= 1) es += __shfl_xor(es, m);
        float inv = 1.f / es;
        #pragma unroll
        for (int i = 0; i < 4; ++i) w_s[tt][l + 16 * i] = ev[i] * inv;
    }
    __syncthreads();

    // ---- out[tok][d] = sum_v w[v] * stacked[tok][v][d]
    {
        int d = t & 63, g = t >> 6;
        #pragma unroll
        for (int i = 0; i < 4; ++i) {
            int tt = g * 4 + i;
            const float* sp = stacked + (size_t)(tok0 + tt) * 4096 + d;
            float acc = 0.f;
            #pragma unroll
            for (int vv = 0; vv < 64; ++vv) acc += w_s[tt][vv] * sp[vv * 64];
            out[(size_t)(tok0 + tt) * 64 + d] = acc;
        }
    }
}

extern "C" void kernel_launch(void* const* d_in, const int* in_sizes, int n_in,
                              void* d_out, int out_size, void* d_ws, size_t ws_size,
                              hipStream_t stream) {
    const float* x     = (const float*)d_in[0];
    const float* W1    = (const float*)d_in[1];
    const float* b1    = (const float*)d_in[2];
    const float* W2    = (const float*)d_in[3];
    const float* b2    = (const float*)d_in[4];
    const float* Wg    = (const float*)d_in[5];
    const float* bg    = (const float*)d_in[6];
    const float* Wsk   = (const float*)d_in[7];
    const float* bsk   = (const float*)d_in[8];
    const float* gamma = (const float*)d_in[9];
    const float* beta  = (const float*)d_in[10];
    const float* Wn1   = (const float*)d_in[11];
    const float* bn1   = (const float*)d_in[12];
    const float* Wn2   = (const float*)d_in[13];
    const float* bn2   = (const float*)d_in[14];
    const float* Wng   = (const float*)d_in[15];
    const float* bng   = (const float*)d_in[16];
    const float* Wns   = (const float*)d_in[17];
    const float* bns   = (const float*)d_in[18];
    const float* ngam  = (const float*)d_in[19];
    const float* nbet  = (const float*)d_in[20];

    float* stacked = (float*)d_ws;                         // 128 MiB
    float* part    = (float*)d_ws + (size_t)NTOK * 4096;   // +16 MiB (4 partials x 8192 x 128)
    float* outp    = (float*)d_out;

    vsn_stage1<<<dim3(NTOK / 64, NV), 256, 0, stream>>>(
        x, W1, b1, W2, b2, Wg, bg, Wsk, bsk, gamma, beta, stacked);
    vsn_stage2a<<<dim3(NTOK / 64, KSPLIT), 128, 0, stream>>>(stacked, Wn1, Wns, part);
    vsn_stage2b<<<dim3(NTOK / 16), 256, 0, stream>>>(
        stacked, part, bn1, Wn2, bn2, Wng, bng, bns, ngam, nbet, outp);
}

// Round 3
// 427.302 us; speedup vs baseline: 3.0308x; 1.8036x over previous
//
#include <hip/hip_runtime.h>
#include <hip/hip_bf16.h>
#include <math.h>

#define NV 64
#define ND 64
#define NTOK 8192
#define LN_EPS 1e-5f
#define KSPLIT 8
#define KRANGE (4096 / KSPLIT)   // 512

typedef __attribute__((ext_vector_type(8))) short s8v;    // 8 bf16 = 4 VGPR
typedef __attribute__((ext_vector_type(4))) float f4v;    // MFMA C/D

__device__ __forceinline__ float elu_f(float x)  { return x > 0.f ? x : expm1f(x); }
__device__ __forceinline__ float sigm_f(float x) { return 1.f / (1.f + expf(-x)); }
__device__ __forceinline__ void f4st(float* d, float4 v){ d[0]=v.x; d[1]=v.y; d[2]=v.z; d[3]=v.w; }

// ---------------- Stage 1: per-variable GRN + LayerNorm -> stacked bf16 [tok][v*64+d]
// (unchanged fp32 compute from round 2; only the final store is bf16)
__global__ __launch_bounds__(256) void vsn_stage1(
    const float* __restrict__ x,
    const float* __restrict__ W1, const float* __restrict__ b1,
    const float* __restrict__ W2, const float* __restrict__ b2,
    const float* __restrict__ Wg, const float* __restrict__ bg,
    const float* __restrict__ Wsk, const float* __restrict__ bsk,
    const float* __restrict__ gamma, const float* __restrict__ beta,
    __hip_bfloat16* __restrict__ stb)
{
    const int t = threadIdx.x;
    const int tile0 = blockIdx.x * 64;
    const int v = blockIdx.y;
    const int nq = t & 15, tq = t >> 4;
    const int e0 = nq * 4, tokl = tq * 4;

    __shared__ __align__(16) float xs[64];
    __shared__ __align__(16) float bufT[64][68];   // [k][token], h1 then h2
    __shared__ __align__(16) float sbuf[64][68];   // [token][e] pre-LN

    if (t < 64) xs[t] = x[(size_t)(tile0 + t) * NV + v];
    __syncthreads();

    float xtok[4];
    f4st(xtok, *(const float4*)&xs[tokl]);

    // h1 = elu(x*W1 + b1), transposed
    {
        float w1[4], bb[4];
        f4st(w1, *(const float4*)(W1 + v * 64 + e0));
        f4st(bb, *(const float4*)(b1 + v * 64 + e0));
        #pragma unroll
        for (int j = 0; j < 4; ++j) {
            float4 o;
            o.x = elu_f(xtok[0] * w1[j] + bb[j]);
            o.y = elu_f(xtok[1] * w1[j] + bb[j]);
            o.z = elu_f(xtok[2] * w1[j] + bb[j]);
            o.w = elu_f(xtok[3] * w1[j] + bb[j]);
            *(float4*)&bufT[e0 + j][tokl] = o;
        }
    }

    // GEMM1: h2 = h1 @ W2_v + b2
    float h2r[4][4];
    {
        float bb[4]; f4st(bb, *(const float4*)(b2 + v * 64 + e0));
        #pragma unroll
        for (int i = 0; i < 4; ++i)
            #pragma unroll
            for (int j = 0; j < 4; ++j) h2r[i][j] = bb[j];
    }
    __syncthreads();
    {
        const float* Wv = W2 + (size_t)v * 4096;
        #pragma unroll 4
        for (int k = 0; k < 64; ++k) {
            float a[4], w[4];
            f4st(a, *(const float4*)&bufT[k][tokl]);
            f4st(w, *(const float4*)(Wv + k * 64 + e0));
            #pragma unroll
            for (int i = 0; i < 4; ++i)
                #pragma unroll
                for (int j = 0; j < 4; ++j) h2r[i][j] += a[i] * w[j];
        }
    }
    __syncthreads();
    #pragma unroll
    for (int j = 0; j < 4; ++j) {
        float4 o = make_float4(h2r[0][j], h2r[1][j], h2r[2][j], h2r[3][j]);
        *(float4*)&bufT[e0 + j][tokl] = o;   // h2 transposed
    }

    // GEMM2: g = sigmoid(h2 @ Wg_v + bg)
    float ga[4][4];
    {
        float bb[4]; f4st(bb, *(const float4*)(bg + v * 64 + e0));
        #pragma unroll
        for (int i = 0; i < 4; ++i)
            #pragma unroll
            for (int j = 0; j < 4; ++j) ga[i][j] = bb[j];
    }
    __syncthreads();
    {
        const float* Wv = Wg + (size_t)v * 4096;
        #pragma unroll 4
        for (int k = 0; k < 64; ++k) {
            float a[4], w[4];
            f4st(a, *(const float4*)&bufT[k][tokl]);
            f4st(w, *(const float4*)(Wv + k * 64 + e0));
            #pragma unroll
            for (int i = 0; i < 4; ++i)
                #pragma unroll
                for (int j = 0; j < 4; ++j) ga[i][j] += a[i] * w[j];
        }
    }

    // s = x*Wsk + bsk + g*h2
    {
        float wsk4[4], bsk4[4];
        f4st(wsk4, *(const float4*)(Wsk + v * 64 + e0));
        f4st(bsk4, *(const float4*)(bsk + v * 64 + e0));
        #pragma unroll
        for (int i = 0; i < 4; ++i) {
            float4 o;
            o.x = xtok[i] * wsk4[0] + bsk4[0] + sigm_f(ga[i][0]) * h2r[i][0];
            o.y = xtok[i] * wsk4[1] + bsk4[1] + sigm_f(ga[i][1]) * h2r[i][1];
            o.z = xtok[i] * wsk4[2] + bsk4[2] + sigm_f(ga[i][2]) * h2r[i][2];
            o.w = xtok[i] * wsk4[3] + bsk4[3] + sigm_f(ga[i][3]) * h2r[i][3];
            *(float4*)&sbuf[tokl + i][e0] = o;
        }
    }
    __syncthreads();

    // LayerNorm over d; 4 lanes per row; bf16 store
    {
        int row = t >> 2, l = t & 3;
        float sum = 0.f, sq = 0.f;
        #pragma unroll
        for (int i = 0; i < 16; ++i) {
            float s0 = sbuf[row][l + 4 * i];
            sum += s0; sq += s0 * s0;
        }
        sum += __shfl_xor(sum, 1); sum += __shfl_xor(sum, 2);
        sq  += __shfl_xor(sq, 1);  sq  += __shfl_xor(sq, 2);
        float mu  = sum * 0.015625f;
        float var = sq * 0.015625f - mu * mu;
        float rs  = rsqrtf(var + LN_EPS);
        size_t base = (size_t)(tile0 + row) * 4096 + (size_t)v * 64;
        #pragma unroll
        for (int i = 0; i < 16; ++i) {
            int ee = l + 4 * i;
            stb[base + ee] = __float2bfloat16(
                (sbuf[row][ee] - mu) * rs * gamma[v * 64 + ee] + beta[v * 64 + ee]);
        }
    }
}

// ---------------- Prepack: Wct[n][k] = concat(Wn1,Wns)[k][n] as bf16 (1 MB, one-shot)
__global__ __launch_bounds__(256) void vsn_prepack(
    const float* __restrict__ Wn1, const float* __restrict__ Wns,
    __hip_bfloat16* __restrict__ wct)
{
    int idx = blockIdx.x * 256 + threadIdx.x;   // 128*4096 elements
    int n = idx >> 12, k = idx & 4095;
    float v = (n < 64) ? Wn1[(size_t)k * 64 + n] : Wns[(size_t)k * 64 + (n - 64)];
    wct[idx] = __float2bfloat16(v);
}

// ---------------- Stage 2a: part[s][tok][0:128] = flat @ [Wn1|Wns] over K-range s
// bf16 MFMA 16x16x32, NO LDS. grid (128 M-tiles, 8 K-splits), block 256 (4 waves).
// Wave w covers n in [w*32, w*32+32) x 64 rows. A,B frags are contiguous 16B loads.
__global__ __launch_bounds__(256) void vsn_stage2a(
    const __hip_bfloat16* __restrict__ stb,   // [8192][4096]
    const __hip_bfloat16* __restrict__ wct,   // [128][4096]  (transposed weights)
    float* __restrict__ part)
{
    const int t = threadIdx.x;
    const int wave = t >> 6, lane = t & 63;
    const int tok0 = blockIdx.x * 64;
    const int s = blockIdx.y;
    const int k0 = s * KRANGE;
    const int m16 = lane & 15, quad = lane >> 4;
    const int n0 = wave * 32;

    const short* A  = (const short*)stb;
    const short* Bw = (const short*)wct;

    f4v acc[4][2];
    #pragma unroll
    for (int i = 0; i < 4; ++i)
        #pragma unroll
        for (int j = 0; j < 2; ++j)
            acc[i][j] = (f4v){0.f, 0.f, 0.f, 0.f};

    const short* arow = A  + (size_t)(tok0 + m16) * 4096 + quad * 8;
    const short* brow = Bw + (size_t)(n0 + m16) * 4096 + quad * 8;

    for (int k = k0; k < k0 + KRANGE; k += 32) {
        s8v a[4], b[2];
        #pragma unroll
        for (int i = 0; i < 4; ++i)
            a[i] = *(const s8v*)(arow + (size_t)i * 16 * 4096 + k);
        #pragma unroll
        for (int j = 0; j < 2; ++j)
            b[j] = *(const s8v*)(brow + (size_t)j * 16 * 4096 + k);
        #pragma unroll
        for (int i = 0; i < 4; ++i)
            #pragma unroll
            for (int j = 0; j < 2; ++j)
                acc[i][j] = __builtin_amdgcn_mfma_f32_16x16x32_bf16(a[i], b[j], acc[i][j], 0, 0, 0);
    }

    // D layout: row m = quad*4 + r, col n = m16
    #pragma unroll
    for (int i = 0; i < 4; ++i)
        #pragma unroll
        for (int j = 0; j < 2; ++j)
            #pragma unroll
            for (int r = 0; r < 4; ++r)
                part[((size_t)s * NTOK + tok0 + i * 16 + quad * 4 + r) * 128
                     + n0 + j * 16 + m16] = acc[i][j][r];
}

// ---------------- Stage 2b: reduce partials, weight-net tail, softmax, weighted sum
__global__ __launch_bounds__(256) void vsn_stage2b(
    const __hip_bfloat16* __restrict__ stb, const float* __restrict__ part,
    const float* __restrict__ bn1,
    const float* __restrict__ Wn2, const float* __restrict__ bn2,
    const float* __restrict__ Wng, const float* __restrict__ bng,
    const float* __restrict__ bns,
    const float* __restrict__ ngamma, const float* __restrict__ nbeta,
    float* __restrict__ out)
{
    const int t = threadIdx.x;
    const int tok0 = blockIdx.x * 16;

    __shared__ __align__(16) float hw1_s[16][64];
    __shared__ float skw_s[16][64];
    __shared__ __align__(16) float hw2_s[16][64];
    __shared__ float s2_s[16][64];
    __shared__ float w_s[16][64];

    // hw1 = elu(sum_s part + bn1), skw = sum_s part + bns
    #pragma unroll
    for (int i = 0; i < 4; ++i) {
        int oidx = i * 256 + t;
        int tt = oidx >> 6, jj = oidx & 63;
        size_t rb = (size_t)(tok0 + tt) * 128;
        float p1 = 0.f, ps = 0.f;
        #pragma unroll
        for (int s = 0; s < KSPLIT; ++s) {
            p1 += part[(size_t)s * NTOK * 128 + rb + jj];
            ps += part[(size_t)s * NTOK * 128 + rb + 64 + jj];
        }
        hw1_s[tt][jj] = elu_f(p1 + bn1[jj]);
        skw_s[tt][jj] = ps + bns[jj];
    }
    __syncthreads();

    // hw2 = hw1 @ Wn2 + bn2
    #pragma unroll
    for (int i = 0; i < 4; ++i) {
        int oidx = i * 256 + t;
        int tt = oidx >> 6, jj = oidx & 63;
        float acc = bn2[jj];
        #pragma unroll
        for (int k4 = 0; k4 < 16; ++k4) {
            float4 h = *(const float4*)&hw1_s[tt][k4 * 4];
            acc += h.x * Wn2[(k4*4+0)*64+jj] + h.y * Wn2[(k4*4+1)*64+jj]
                 + h.z * Wn2[(k4*4+2)*64+jj] + h.w * Wn2[(k4*4+3)*64+jj];
        }
        hw2_s[tt][jj] = acc;
    }
    __syncthreads();

    // gw = sigmoid(hw2 @ Wng + bng); s2 = skw + gw*hw2
    #pragma unroll
    for (int i = 0; i < 4; ++i) {
        int oidx = i * 256 + t;
        int tt = oidx >> 6, vv = oidx & 63;
        float acc = bng[vv];
        #pragma unroll
        for (int k4 = 0; k4 < 16; ++k4) {
            float4 h = *(const float4*)&hw2_s[tt][k4 * 4];
            acc += h.x * Wng[(k4*4+0)*64+vv] + h.y * Wng[(k4*4+1)*64+vv]
                 + h.z * Wng[(k4*4+2)*64+vv] + h.w * Wng[(k4*4+3)*64+vv];
        }
        float gw = sigm_f(acc);
        s2_s[tt][vv] = skw_s[tt][vv] + gw * hw2_s[tt][vv];
    }
    __syncthreads();

    // LN over v + softmax; 16 lanes per token
    {
        int tt = t >> 4, l = t & 15;
        float z[4]; float sum = 0.f, sq = 0.f;
        #pragma unroll
        for (int i = 0; i < 4; ++i) { z[i] = s2_s[tt][l + 16 * i]; sum += z[i]; sq += z[i] * z[i]; }
        #pragma unroll
        for (int m = 1; m < 16; m <<= 1) { sum += __shfl_xor(sum, m); sq += __shfl_xor(sq, m); }
        float mu  = sum * 0.015625f;
        float var = sq * 0.015625f - mu * mu;
        float rs  = rsqrtf(var + LN_EPS);
        float ln[4]; float mx = -1e30f;
        #pragma unroll
        for (int i = 0; i < 4; ++i) {
            ln[i] = (z[i] - mu) * rs * ngamma[l + 16 * i] + nbeta[l + 16 * i];
            mx = fmaxf(mx, ln[i]);
        }
        #pragma unroll
        for (int m = 1; m < 16; m <<= 1) mx = fmaxf(mx, __shfl_xor(mx, m));
        float es = 0.f; float ev[4];
        #pragma unroll
        for (int i = 0; i < 4; ++i) { ev[i] = expf(ln[i] - mx); es += ev[i]; }
        #pragma unroll
        for (int m = 1; m < 16; m <<= 1) es += __shfl_xor(es, m);
        float inv = 1.f / es;
        #pragma unroll
        for (int i = 0; i < 4; ++i) w_s[tt][l + 16 * i] = ev[i] * inv;
    }
    __syncthreads();

    // out[tok][d] = sum_v w[v] * stacked[tok][v][d]   (bf16 reads)
    {
        int d = t & 63, g = t >> 6;
        #pragma unroll
        for (int i = 0; i < 4; ++i) {
            int tt = g * 4 + i;
            const __hip_bfloat16* sp = stb + (size_t)(tok0 + tt) * 4096 + d;
            float acc = 0.f;
            #pragma unroll
            for (int vv = 0; vv < 64; ++vv) acc += w_s[tt][vv] * __bfloat162float(sp[vv * 64]);
            out[(size_t)(tok0 + tt) * 64 + d] = acc;
        }
    }
}

extern "C" void kernel_launch(void* const* d_in, const int* in_sizes, int n_in,
                              void* d_out, int out_size, void* d_ws, size_t ws_size,
                              hipStream_t stream) {
    const float* x     = (const float*)d_in[0];
    const float* W1    = (const float*)d_in[1];
    const float* b1    = (const float*)d_in[2];
    const float* W2    = (const float*)d_in[3];
    const float* b2    = (const float*)d_in[4];
    const float* Wg    = (const float*)d_in[5];
    const float* bg    = (const float*)d_in[6];
    const float* Wsk   = (const float*)d_in[7];
    const float* bsk   = (const float*)d_in[8];
    const float* gamma = (const float*)d_in[9];
    const float* beta  = (const float*)d_in[10];
    const float* Wn1   = (const float*)d_in[11];
    const float* bn1   = (const float*)d_in[12];
    const float* Wn2   = (const float*)d_in[13];
    const float* bn2   = (const float*)d_in[14];
    const float* Wng   = (const float*)d_in[15];
    const float* bng   = (const float*)d_in[16];
    const float* Wns   = (const float*)d_in[17];
    const float* bns   = (const float*)d_in[18];
    const float* ngam  = (const float*)d_in[19];
    const float* nbet  = (const float*)d_in[20];

    __hip_bfloat16* stb = (__hip_bfloat16*)d_ws;              // 64 MiB
    __hip_bfloat16* wct = stb + (size_t)NTOK * 4096;          // +1 MiB
    float* part = (float*)(wct + (size_t)128 * 4096);         // +32 MiB (8 x 8192 x 128)
    float* outp = (float*)d_out;

    vsn_stage1<<<dim3(NTOK / 64, NV), 256, 0, stream>>>(
        x, W1, b1, W2, b2, Wg, bg, Wsk, bsk, gamma, beta, stb);
    vsn_prepack<<<dim3(128 * 4096 / 256), 256, 0, stream>>>(Wn1, Wns, wct);
    vsn_stage2a<<<dim3(NTOK / 64, KSPLIT), 256, 0, stream>>>(stb, wct, part);
    vsn_stage2b<<<dim3(NTOK / 16), 256, 0, stream>>>(
        stb, part, bn1, Wn2, bn2, Wng, bng, bns, ngam, nbet, outp);
}

// Round 4
// 341.431 us; speedup vs baseline: 3.7930x; 1.2515x over previous
//
#include <hip/hip_runtime.h>
#include <hip/hip_bf16.h>
#include <math.h>

#define NV 64
#define ND 64
#define NTOK 8192
#define LN_EPS 1e-5f
#define KSPLIT 8
#define KRANGE (4096 / KSPLIT)   // 512

typedef __attribute__((ext_vector_type(8))) short s8v;    // 8 bf16 = 4 VGPR
typedef __attribute__((ext_vector_type(4))) float f4v;    // MFMA C/D
typedef __attribute__((ext_vector_type(4))) int   i4v;

__device__ __forceinline__ float sigm_f(float x) { return 1.f / (1.f + __expf(-x)); }
__device__ __forceinline__ float elu_f(float x)  { return x > 0.f ? x : (__expf(x) - 1.f); }
__device__ __forceinline__ void f4st(float* d, float4 v){ d[0]=v.x; d[1]=v.y; d[2]=v.z; d[3]=v.w; }

__device__ __forceinline__ unsigned short bf16_rne(float f) {
    union { float f; unsigned int u; } c; c.f = f;
    return (unsigned short)((c.u + 0x7fffu + ((c.u >> 16) & 1u)) >> 16);
}
__device__ __forceinline__ float bf16_to_f(unsigned short s) {
    union { unsigned int u; float f; } c; c.u = ((unsigned int)s) << 16;
    return c.f;
}

// ---------------- Prepack W2/Wg: [v][d][e] -> transposed bf16 hi/lo [v][e][d]
__global__ __launch_bounds__(256) void vsn_prepack_w(
    const float* __restrict__ W2, const float* __restrict__ Wg,
    short* __restrict__ w2h, short* __restrict__ w2l,
    short* __restrict__ wgh, short* __restrict__ wgl)
{
    int idx = blockIdx.x * 256 + threadIdx.x;        // 64*64*64 = 262144
    int v = idx >> 12, d = (idx >> 6) & 63, e = idx & 63;
    size_t dst = ((size_t)v * 64 + e) * 64 + d;
    float a = W2[idx];
    unsigned short h = bf16_rne(a);
    w2h[dst] = (short)h; w2l[dst] = (short)bf16_rne(a - bf16_to_f(h));
    float g = Wg[idx];
    h = bf16_rne(g);
    wgh[dst] = (short)h; wgl[dst] = (short)bf16_rne(g - bf16_to_f(h));
}

// ---------------- Prepack weight-net: Wct[n][k] = concat(Wn1,Wns)[k][n] bf16
__global__ __launch_bounds__(256) void vsn_prepack_n(
    const float* __restrict__ Wn1, const float* __restrict__ Wns,
    __hip_bfloat16* __restrict__ wct)
{
    int idx = blockIdx.x * 256 + threadIdx.x;   // 128*4096
    int n = idx >> 12, k = idx & 4095;
    float v = (n < 64) ? Wn1[(size_t)k * 64 + n] : Wns[(size_t)k * 64 + (n - 64)];
    wct[idx] = __float2bfloat16(v);
}

// ---------------- Stage 1: per-variable GRN + LN via bf16x3 MFMA -> stacked bf16
// block = 4 waves; wave w handles 32 tokens x variable (by*4+w).
// grid (256 token-tiles, 16 var-groups).
__global__ __launch_bounds__(256) void vsn_stage1(
    const float* __restrict__ x,
    const float* __restrict__ W1, const float* __restrict__ b1,
    const short* __restrict__ w2h, const short* __restrict__ w2l,
    const short* __restrict__ wgh, const short* __restrict__ wgl,
    const float* __restrict__ b2, const float* __restrict__ bg,
    const float* __restrict__ Wsk, const float* __restrict__ bsk,
    const float* __restrict__ gamma, const float* __restrict__ beta,
    __hip_bfloat16* __restrict__ stb)
{
    const int t = threadIdx.x;
    const int wave = t >> 6, lane = t & 63;
    const int m16 = lane & 15, quad = lane >> 4;
    const int tile0 = blockIdx.x * 32;
    const int v = blockIdx.y * 4 + wave;

    __shared__ float xs[4][32];
    __shared__ unsigned int h2l[4][32][68];   // packed (hi | lo<<16) h2, per-wave region

    if (lane < 32) xs[wave][lane] = x[(size_t)(tile0 + lane) * NV + v];
    // same-wave LDS RAW: compiler inserts lgkmcnt wait; no barrier needed.

    // ---- h1 fragments: A[m=lane&15][k=quad*8+j], bf16 hi/lo split
    s8v a_h[2][2], a_l[2][2];
    #pragma unroll
    for (int kt = 0; kt < 2; ++kt) {
        float w1k[8], b1k[8];
        *(float4*)&w1k[0] = *(const float4*)(W1 + v * 64 + kt * 32 + quad * 8);
        *(float4*)&w1k[4] = *(const float4*)(W1 + v * 64 + kt * 32 + quad * 8 + 4);
        *(float4*)&b1k[0] = *(const float4*)(b1 + v * 64 + kt * 32 + quad * 8);
        *(float4*)&b1k[4] = *(const float4*)(b1 + v * 64 + kt * 32 + quad * 8 + 4);
        #pragma unroll
        for (int mi = 0; mi < 2; ++mi) {
            float xv = xs[wave][mi * 16 + m16];
            #pragma unroll
            for (int j = 0; j < 8; ++j) {
                float h = elu_f(fmaf(xv, w1k[j], b1k[j]));
                unsigned short hb = bf16_rne(h);
                a_h[mi][kt][j] = (short)hb;
                a_l[mi][kt][j] = (short)bf16_rne(h - bf16_to_f(hb));
            }
        }
    }

    // ---- GEMM1 (bf16x3): h2 = h1 @ W2_v + b2
    f4v hacc[2][4];
    #pragma unroll
    for (int mi = 0; mi < 2; ++mi)
        #pragma unroll
        for (int ni = 0; ni < 4; ++ni) hacc[mi][ni] = (f4v){0.f, 0.f, 0.f, 0.f};

    const size_t wb = (size_t)v * 4096;
    #pragma unroll
    for (int ni = 0; ni < 4; ++ni) {
        #pragma unroll
        for (int kt = 0; kt < 2; ++kt) {
            size_t off = wb + (size_t)(ni * 16 + m16) * 64 + kt * 32 + quad * 8;
            s8v bh = *(const s8v*)(w2h + off);
            s8v bl = *(const s8v*)(w2l + off);
            #pragma unroll
            for (int mi = 0; mi < 2; ++mi) {
                hacc[mi][ni] = __builtin_amdgcn_mfma_f32_16x16x32_bf16(a_h[mi][kt], bh, hacc[mi][ni], 0, 0, 0);
                hacc[mi][ni] = __builtin_amdgcn_mfma_f32_16x16x32_bf16(a_l[mi][kt], bh, hacc[mi][ni], 0, 0, 0);
                hacc[mi][ni] = __builtin_amdgcn_mfma_f32_16x16x32_bf16(a_h[mi][kt], bl, hacc[mi][ni], 0, 0, 0);
            }
        }
    }
    {
        float b2d[4];
        #pragma unroll
        for (int ni = 0; ni < 4; ++ni) b2d[ni] = b2[v * 64 + ni * 16 + m16];
        #pragma unroll
        for (int mi = 0; mi < 2; ++mi)
            #pragma unroll
            for (int ni = 0; ni < 4; ++ni)
                #pragma unroll
                for (int r = 0; r < 4; ++r) hacc[mi][ni][r] += b2d[ni];
    }

    // ---- h2: C-layout -> LDS (packed hi|lo) -> A-layout fragments
    #pragma unroll
    for (int mi = 0; mi < 2; ++mi)
        #pragma unroll
        for (int ni = 0; ni < 4; ++ni)
            #pragma unroll
            for (int r = 0; r < 4; ++r) {
                float h2v = hacc[mi][ni][r];
                unsigned int hb = bf16_rne(h2v);
                unsigned int lb = bf16_rne(h2v - bf16_to_f((unsigned short)hb));
                h2l[wave][mi * 16 + quad * 4 + r][ni * 16 + m16] = hb | (lb << 16);
            }
    // same-wave RAW again; no barrier.
    s8v c_h[2][2], c_l[2][2];
    #pragma unroll
    for (int mi = 0; mi < 2; ++mi)
        #pragma unroll
        for (int kt = 0; kt < 2; ++kt) {
            const unsigned int* p = &h2l[wave][mi * 16 + m16][kt * 32 + quad * 8];
            i4v q0 = *(const i4v*)p;
            i4v q1 = *(const i4v*)(p + 4);
            #pragma unroll
            for (int j = 0; j < 4; ++j) {
                c_h[mi][kt][j]     = (short)(q0[j] & 0xffff);
                c_l[mi][kt][j]     = (short)(((unsigned int)q0[j]) >> 16);
                c_h[mi][kt][4 + j] = (short)(q1[j] & 0xffff);
                c_l[mi][kt][4 + j] = (short)(((unsigned int)q1[j]) >> 16);
            }
        }

    // ---- GEMM2 (bf16x3): g = sigmoid(h2 @ Wg_v + bg)
    f4v gacc[2][4];
    #pragma unroll
    for (int mi = 0; mi < 2; ++mi)
        #pragma unroll
        for (int ni = 0; ni < 4; ++ni) gacc[mi][ni] = (f4v){0.f, 0.f, 0.f, 0.f};
    #pragma unroll
    for (int ni = 0; ni < 4; ++ni) {
        #pragma unroll
        for (int kt = 0; kt < 2; ++kt) {
            size_t off = wb + (size_t)(ni * 16 + m16) * 64 + kt * 32 + quad * 8;
            s8v bh = *(const s8v*)(wgh + off);
            s8v bl = *(const s8v*)(wgl + off);
            #pragma unroll
            for (int mi = 0; mi < 2; ++mi) {
                gacc[mi][ni] = __builtin_amdgcn_mfma_f32_16x16x32_bf16(c_h[mi][kt], bh, gacc[mi][ni], 0, 0, 0);
                gacc[mi][ni] = __builtin_amdgcn_mfma_f32_16x16x32_bf16(c_l[mi][kt], bh, gacc[mi][ni], 0, 0, 0);
                gacc[mi][ni] = __builtin_amdgcn_mfma_f32_16x16x32_bf16(c_h[mi][kt], bl, gacc[mi][ni], 0, 0, 0);
            }
        }
    }

    // ---- s = x*Wsk + bsk + sigm(g)*h2  (in C-layout, into gacc)
    {
        float bgd[4], wskd[4], bskd[4];
        #pragma unroll
        for (int ni = 0; ni < 4; ++ni) {
            int d = v * 64 + ni * 16 + m16;
            bgd[ni] = bg[d]; wskd[ni] = Wsk[d]; bskd[ni] = bsk[d];
        }
        float xtok[2][4];
        #pragma unroll
        for (int mi = 0; mi < 2; ++mi)
            #pragma unroll
            for (int r = 0; r < 4; ++r) xtok[mi][r] = xs[wave][mi * 16 + quad * 4 + r];
        #pragma unroll
        for (int mi = 0; mi < 2; ++mi)
            #pragma unroll
            for (int ni = 0; ni < 4; ++ni)
                #pragma unroll
                for (int r = 0; r < 4; ++r) {
                    float g = sigm_f(gacc[mi][ni][r] + bgd[ni]);
                    gacc[mi][ni][r] = fmaf(xtok[mi][r], wskd[ni], bskd[ni]) + g * hacc[mi][ni][r];
                }
    }

    // ---- LayerNorm over d (16-lane shuffle) + bf16 store
    {
        float gamd[4], betd[4];
        #pragma unroll
        for (int ni = 0; ni < 4; ++ni) {
            int d = v * 64 + ni * 16 + m16;
            gamd[ni] = gamma[d]; betd[ni] = beta[d];
        }
        #pragma unroll
        for (int mi = 0; mi < 2; ++mi)
            #pragma unroll
            for (int r = 0; r < 4; ++r) {
                float s0 = gacc[mi][0][r], s1 = gacc[mi][1][r], s2 = gacc[mi][2][r], s3 = gacc[mi][3][r];
                float sum = s0 + s1 + s2 + s3;
                float sq  = s0 * s0 + s1 * s1 + s2 * s2 + s3 * s3;
                #pragma unroll
                for (int m = 1; m < 16; m <<= 1) { sum += __shfl_xor(sum, m); sq += __shfl_xor(sq, m); }
                float mu  = sum * 0.015625f;
                float var = sq * 0.015625f - mu * mu;
                float rs  = rsqrtf(var + LN_EPS);
                size_t base = (size_t)(tile0 + mi * 16 + quad * 4 + r) * 4096 + (size_t)v * 64 + m16;
                #pragma unroll
                for (int ni = 0; ni < 4; ++ni)
                    stb[base + ni * 16] = __float2bfloat16(
                        (gacc[mi][ni][r] - mu) * rs * gamd[ni] + betd[ni]);
            }
    }
}

// ---------------- Stage 2a: part[s][tok][0:128] = flat @ [Wn1|Wns] over K-range s
// bf16 MFMA 16x16x32, NO LDS. grid (128 M-tiles, 8 K-splits), block 256 (4 waves).
__global__ __launch_bounds__(256) void vsn_stage2a(
    const __hip_bfloat16* __restrict__ stb,   // [8192][4096]
    const __hip_bfloat16* __restrict__ wct,   // [128][4096]
    float* __restrict__ part)
{
    const int t = threadIdx.x;
    const int wave = t >> 6, lane = t & 63;
    const int tok0 = blockIdx.x * 64;
    const int s = blockIdx.y;
    const int k0 = s * KRANGE;
    const int m16 = lane & 15, quad = lane >> 4;
    const int n0 = wave * 32;

    const short* A  = (const short*)stb;
    const short* Bw = (const short*)wct;

    f4v acc[4][2];
    #pragma unroll
    for (int i = 0; i < 4; ++i)
        #pragma unroll
        for (int j = 0; j < 2; ++j)
            acc[i][j] = (f4v){0.f, 0.f, 0.f, 0.f};

    const short* arow = A  + (size_t)(tok0 + m16) * 4096 + quad * 8;
    const short* brow = Bw + (size_t)(n0 + m16) * 4096 + quad * 8;

    for (int k = k0; k < k0 + KRANGE; k += 32) {
        s8v a[4], b[2];
        #pragma unroll
        for (int i = 0; i < 4; ++i)
            a[i] = *(const s8v*)(arow + (size_t)i * 16 * 4096 + k);
        #pragma unroll
        for (int j = 0; j < 2; ++j)
            b[j] = *(const s8v*)(brow + (size_t)j * 16 * 4096 + k);
        #pragma unroll
        for (int i = 0; i < 4; ++i)
            #pragma unroll
            for (int j = 0; j < 2; ++j)
                acc[i][j] = __builtin_amdgcn_mfma_f32_16x16x32_bf16(a[i], b[j], acc[i][j], 0, 0, 0);
    }

    #pragma unroll
    for (int i = 0; i < 4; ++i)
        #pragma unroll
        for (int j = 0; j < 2; ++j)
            #pragma unroll
            for (int r = 0; r < 4; ++r)
                part[((size_t)s * NTOK + tok0 + i * 16 + quad * 4 + r) * 128
                     + n0 + j * 16 + m16] = acc[i][j][r];
}

// ---------------- Stage 2b: reduce partials, weight-net tail, softmax, weighted sum
__global__ __launch_bounds__(256) void vsn_stage2b(
    const __hip_bfloat16* __restrict__ stb, const float* __restrict__ part,
    const float* __restrict__ bn1,
    const float* __restrict__ Wn2, const float* __restrict__ bn2,
    const float* __restrict__ Wng, const float* __restrict__ bng,
    const float* __restrict__ bns,
    const float* __restrict__ ngamma, const float* __restrict__ nbeta,
    float* __restrict__ out)
{
    const int t = threadIdx.x;
    const int tok0 = blockIdx.x * 16;

    __shared__ __align__(16) float hw1_s[16][64];
    __shared__ float skw_s[16][64];
    __shared__ __align__(16) float hw2_s[16][64];
    __shared__ float s2_s[16][64];
    __shared__ float w_s[16][64];

    #pragma unroll
    for (int i = 0; i < 4; ++i) {
        int oidx = i * 256 + t;
        int tt = oidx >> 6, jj = oidx & 63;
        size_t rb = (size_t)(tok0 + tt) * 128;
        float p1 = 0.f, ps = 0.f;
        #pragma unroll
        for (int s = 0; s < KSPLIT; ++s) {
            p1 += part[(size_t)s * NTOK * 128 + rb + jj];
            ps += part[(size_t)s * NTOK * 128 + rb + 64 + jj];
        }
        hw1_s[tt][jj] = elu_f(p1 + bn1[jj]);
        skw_s[tt][jj] = ps + bns[jj];
    }
    __syncthreads();

    #pragma unroll
    for (int i = 0; i < 4; ++i) {
        int oidx = i * 256 + t;
        int tt = oidx >> 6, jj = oidx & 63;
        float acc = bn2[jj];
        #pragma unroll
        for (int k4 = 0; k4 < 16; ++k4) {
            float4 h = *(const float4*)&hw1_s[tt][k4 * 4];
            acc += h.x * Wn2[(k4*4+0)*64+jj] + h.y * Wn2[(k4*4+1)*64+jj]
                 + h.z * Wn2[(k4*4+2)*64+jj] + h.w * Wn2[(k4*4+3)*64+jj];
        }
        hw2_s[tt][jj] = acc;
    }
    __syncthreads();

    #pragma unroll
    for (int i = 0; i < 4; ++i) {
        int oidx = i * 256 + t;
        int tt = oidx >> 6, vv = oidx & 63;
        float acc = bng[vv];
        #pragma unroll
        for (int k4 = 0; k4 < 16; ++k4) {
            float4 h = *(const float4*)&hw2_s[tt][k4 * 4];
            acc += h.x * Wng[(k4*4+0)*64+vv] + h.y * Wng[(k4*4+1)*64+vv]
                 + h.z * Wng[(k4*4+2)*64+vv] + h.w * Wng[(k4*4+3)*64+vv];
        }
        float gw = sigm_f(acc);
        s2_s[tt][vv] = skw_s[tt][vv] + gw * hw2_s[tt][vv];
    }
    __syncthreads();

    {
        int tt = t >> 4, l = t & 15;
        float z[4]; float sum = 0.f, sq = 0.f;
        #pragma unroll
        for (int i = 0; i < 4; ++i) { z[i] = s2_s[tt][l + 16 * i]; sum += z[i]; sq += z[i] * z[i]; }
        #pragma unroll
        for (int m = 1; m < 16; m <<= 1) { sum += __shfl_xor(sum, m); sq += __shfl_xor(sq, m); }
        float mu  = sum * 0.015625f;
        float var = sq * 0.015625f - mu * mu;
        float rs  = rsqrtf(var + LN_EPS);
        float ln[4]; float mx = -1e30f;
        #pragma unroll
        for (int i = 0; i < 4; ++i) {
            ln[i] = (z[i] - mu) * rs * ngamma[l + 16 * i] + nbeta[l + 16 * i];
            mx = fmaxf(mx, ln[i]);
        }
        #pragma unroll
        for (int m = 1; m < 16; m <<= 1) mx = fmaxf(mx, __shfl_xor(mx, m));
        float es = 0.f; float ev[4];
        #pragma unroll
        for (int i = 0; i < 4; ++i) { ev[i] = __expf(ln[i] - mx); es += ev[i]; }
        #pragma unroll
        for (int m = 1; m < 16; m <<= 1) es += __shfl_xor(es, m);
        float inv = 1.f / es;
        #pragma unroll
        for (int i = 0; i < 4; ++i) w_s[tt][l + 16 * i] = ev[i] * inv;
    }
    __syncthreads();

    {
        int d = t & 63, g = t >> 6;
        #pragma unroll
        for (int i = 0; i < 4; ++i) {
            int tt = g * 4 + i;
            const __hip_bfloat16* sp = stb + (size_t)(tok0 + tt) * 4096 + d;
            float acc = 0.f;
            #pragma unroll
            for (int vv = 0; vv < 64; ++vv) acc += w_s[tt][vv] * __bfloat162float(sp[vv * 64]);
            out[(size_t)(tok0 + tt) * 64 + d] = acc;
        }
    }
}

extern "C" void kernel_launch(void* const* d_in, const int* in_sizes, int n_in,
                              void* d_out, int out_size, void* d_ws, size_t ws_size,
                              hipStream_t stream) {
    const float* x     = (const float*)d_in[0];
    const float* W1    = (const float*)d_in[1];
    const float* b1    = (const float*)d_in[2];
    const float* W2    = (const float*)d_in[3];
    const float* b2    = (const float*)d_in[4];
    const float* Wg    = (const float*)d_in[5];
    const float* bg    = (const float*)d_in[6];
    const float* Wsk   = (const float*)d_in[7];
    const float* bsk   = (const float*)d_in[8];
    const float* gamma = (const float*)d_in[9];
    const float* beta  = (const float*)d_in[10];
    const float* Wn1   = (const float*)d_in[11];
    const float* bn1   = (const float*)d_in[12];
    const float* Wn2   = (const float*)d_in[13];
    const float* bn2   = (const float*)d_in[14];
    const float* Wng   = (const float*)d_in[15];
    const float* bng   = (const float*)d_in[16];
    const float* Wns   = (const float*)d_in[17];
    const float* bns   = (const float*)d_in[18];
    const float* ngam  = (const float*)d_in[19];
    const float* nbet  = (const float*)d_in[20];

    char* ws = (char*)d_ws;
    __hip_bfloat16* stb = (__hip_bfloat16*)ws;                       // 64 MiB
    __hip_bfloat16* wct = (__hip_bfloat16*)(ws + (64u << 20));       // 1 MiB
    float* part = (float*)(ws + (65u << 20));                        // 32 MiB
    short* w2h = (short*)(ws + (97u << 20));                         // 512 KiB each
    short* w2l = w2h + 262144;
    short* wgh = w2l + 262144;
    short* wgl = wgh + 262144;
    float* outp = (float*)d_out;

    vsn_prepack_w<<<dim3(262144 / 256), 256, 0, stream>>>(W2, Wg, w2h, w2l, wgh, wgl);
    vsn_prepack_n<<<dim3(128 * 4096 / 256), 256, 0, stream>>>(Wn1, Wns, wct);
    vsn_stage1<<<dim3(NTOK / 32, 16), 256, 0, stream>>>(
        x, W1, b1, w2h, w2l, wgh, wgl, b2, bg, Wsk, bsk, gamma, beta, stb);
    vsn_stage2a<<<dim3(NTOK / 64, KSPLIT), 256, 0, stream>>>(stb, wct, part);
    vsn_stage2b<<<dim3(NTOK / 16), 256, 0, stream>>>(
        stb, part, bn1, Wn2, bn2, Wng, bng, bns, ngam, nbet, outp);
}

// Round 5
// 265.129 us; speedup vs baseline: 4.8846x; 1.2878x over previous
//
#include <hip/hip_runtime.h>
#include <hip/hip_bf16.h>
#include <math.h>

#define NV 64
#define ND 64
#define NTOK 8192
#define LN_EPS 1e-5f
#define KSPLIT 8
#define KRANGE (4096 / KSPLIT)   // 512

typedef __attribute__((ext_vector_type(8))) short s8v;    // 8 bf16 = 4 VGPR
typedef __attribute__((ext_vector_type(4))) float f4v;    // MFMA C/D
typedef __attribute__((ext_vector_type(4))) int   i4v;

__device__ __forceinline__ float sigm_f(float x) { return 1.f / (1.f + __expf(-x)); }
__device__ __forceinline__ float elu_f(float x)  { return x > 0.f ? x : (__expf(x) - 1.f); }

__device__ __forceinline__ float bf16_to_f(unsigned short s) {
    union { unsigned int u; float f; } c; c.u = ((unsigned int)s) << 16;
    return c.f;
}
// truncation split: hi = top16(f); lo = top16(f - hi). hi+lo = f + O(2^-16 |f|).
__device__ __forceinline__ void split_tr(float f, short& hi, short& lo) {
    union { float f; unsigned int u; } c; c.f = f;
    hi = (short)(c.u >> 16);
    union { unsigned int u; float f; } h; h.u = c.u & 0xffff0000u;
    union { float f; unsigned int u; } r; r.f = f - h.f;
    lo = (short)(r.u >> 16);
}
__device__ __forceinline__ unsigned int split_pack(float f) {
    union { float f; unsigned int u; } c; c.f = f;
    union { unsigned int u; float f; } h; h.u = c.u & 0xffff0000u;
    union { float f; unsigned int u; } r; r.f = f - h.f;
    return (c.u >> 16) | (r.u & 0xffff0000u);
}

// ---------------- Prepack (merged): W2/Wg hi/lo transpose + weight-net transpose
__global__ __launch_bounds__(256) void vsn_prepack(
    const float* __restrict__ W2, const float* __restrict__ Wg,
    short* __restrict__ w2h, short* __restrict__ w2l,
    short* __restrict__ wgh, short* __restrict__ wgl,
    const float* __restrict__ Wn1, const float* __restrict__ Wns,
    __hip_bfloat16* __restrict__ wct)
{
    int b = blockIdx.x;
    if (b < 1024) {                       // W2/Wg: [v][d][e] -> [v][e][d] hi/lo
        int idx = b * 256 + threadIdx.x;  // 262144
        int v = idx >> 12, d = (idx >> 6) & 63, e = idx & 63;
        size_t dst = ((size_t)v * 64 + e) * 64 + d;
        short h, l;
        split_tr(W2[idx], h, l); w2h[dst] = h; w2l[dst] = l;
        split_tr(Wg[idx], h, l); wgh[dst] = h; wgl[dst] = l;
    } else {                              // Wct[n][k] = concat(Wn1,Wns)[k][n]
        int idx = (b - 1024) * 256 + threadIdx.x;   // 524288
        int n = idx >> 12, k = idx & 4095;
        float v = (n < 64) ? Wn1[(size_t)k * 64 + n] : Wns[(size_t)k * 64 + (n - 64)];
        wct[idx] = __float2bfloat16(v);
    }
}

// ---------------- Stage 1: per-variable GRN + LN via split-bf16 MFMA -> stacked bf16
__global__ __launch_bounds__(256) void vsn_stage1(
    const float* __restrict__ x,
    const float* __restrict__ W1, const float* __restrict__ b1,
    const short* __restrict__ w2h, const short* __restrict__ w2l,
    const short* __restrict__ wgh, const short* __restrict__ wgl,
    const float* __restrict__ b2, const float* __restrict__ bg,
    const float* __restrict__ Wsk, const float* __restrict__ bsk,
    const float* __restrict__ gamma, const float* __restrict__ beta,
    __hip_bfloat16* __restrict__ stb)
{
    const int t = threadIdx.x;
    const int wave = t >> 6, lane = t & 63;
    const int m16 = lane & 15, quad = lane >> 4;
    const int tile0 = blockIdx.x * 32;
    const int v = blockIdx.y * 4 + wave;

    __shared__ float xs[4][32];
    __shared__ unsigned int h2l[4][32][68];   // packed (hi | lo<<16) h2, per-wave

    if (lane < 32) xs[wave][lane] = x[(size_t)(tile0 + lane) * NV + v];

    // ---- h1 fragments: A[m=lane&15][k=quad*8+j], trunc hi/lo split
    s8v a_h[2][2], a_l[2][2];
    #pragma unroll
    for (int kt = 0; kt < 2; ++kt) {
        float w1k[8], b1k[8];
        *(float4*)&w1k[0] = *(const float4*)(W1 + v * 64 + kt * 32 + quad * 8);
        *(float4*)&w1k[4] = *(const float4*)(W1 + v * 64 + kt * 32 + quad * 8 + 4);
        *(float4*)&b1k[0] = *(const float4*)(b1 + v * 64 + kt * 32 + quad * 8);
        *(float4*)&b1k[4] = *(const float4*)(b1 + v * 64 + kt * 32 + quad * 8 + 4);
        #pragma unroll
        for (int mi = 0; mi < 2; ++mi) {
            float xv = xs[wave][mi * 16 + m16];
            #pragma unroll
            for (int j = 0; j < 8; ++j) {
                float h = elu_f(fmaf(xv, w1k[j], b1k[j]));
                short hh, ll; split_tr(h, hh, ll);
                a_h[mi][kt][j] = hh; a_l[mi][kt][j] = ll;
            }
        }
    }

    // ---- GEMM1 (split x3): h2 = h1 @ W2_v + b2
    f4v hacc[2][4];
    #pragma unroll
    for (int mi = 0; mi < 2; ++mi)
        #pragma unroll
        for (int ni = 0; ni < 4; ++ni) hacc[mi][ni] = (f4v){0.f, 0.f, 0.f, 0.f};

    const size_t wb = (size_t)v * 4096;
    #pragma unroll
    for (int ni = 0; ni < 4; ++ni) {
        #pragma unroll
        for (int kt = 0; kt < 2; ++kt) {
            size_t off = wb + (size_t)(ni * 16 + m16) * 64 + kt * 32 + quad * 8;
            s8v bh = *(const s8v*)(w2h + off);
            s8v bl = *(const s8v*)(w2l + off);
            #pragma unroll
            for (int mi = 0; mi < 2; ++mi) {
                hacc[mi][ni] = __builtin_amdgcn_mfma_f32_16x16x32_bf16(a_h[mi][kt], bh, hacc[mi][ni], 0, 0, 0);
                hacc[mi][ni] = __builtin_amdgcn_mfma_f32_16x16x32_bf16(a_l[mi][kt], bh, hacc[mi][ni], 0, 0, 0);
                hacc[mi][ni] = __builtin_amdgcn_mfma_f32_16x16x32_bf16(a_h[mi][kt], bl, hacc[mi][ni], 0, 0, 0);
            }
        }
    }
    {
        float b2d[4];
        #pragma unroll
        for (int ni = 0; ni < 4; ++ni) b2d[ni] = b2[v * 64 + ni * 16 + m16];
        #pragma unroll
        for (int mi = 0; mi < 2; ++mi)
            #pragma unroll
            for (int ni = 0; ni < 4; ++ni)
                #pragma unroll
                for (int r = 0; r < 4; ++r) hacc[mi][ni][r] += b2d[ni];
    }

    // ---- h2: C-layout -> LDS (packed hi|lo) -> A-layout fragments (same-wave RAW)
    #pragma unroll
    for (int mi = 0; mi < 2; ++mi)
        #pragma unroll
        for (int ni = 0; ni < 4; ++ni)
            #pragma unroll
            for (int r = 0; r < 4; ++r)
                h2l[wave][mi * 16 + quad * 4 + r][ni * 16 + m16] = split_pack(hacc[mi][ni][r]);

    s8v c_h[2][2], c_l[2][2];
    #pragma unroll
    for (int mi = 0; mi < 2; ++mi)
        #pragma unroll
        for (int kt = 0; kt < 2; ++kt) {
            const unsigned int* p = &h2l[wave][mi * 16 + m16][kt * 32 + quad * 8];
            i4v q0 = *(const i4v*)p;
            i4v q1 = *(const i4v*)(p + 4);
            #pragma unroll
            for (int j = 0; j < 4; ++j) {
                c_h[mi][kt][j]     = (short)(q0[j] & 0xffff);
                c_l[mi][kt][j]     = (short)(((unsigned int)q0[j]) >> 16);
                c_h[mi][kt][4 + j] = (short)(q1[j] & 0xffff);
                c_l[mi][kt][4 + j] = (short)(((unsigned int)q1[j]) >> 16);
            }
        }

    // ---- GEMM2 (split x3): g = sigmoid(h2 @ Wg_v + bg)
    f4v gacc[2][4];
    #pragma unroll
    for (int mi = 0; mi < 2; ++mi)
        #pragma unroll
        for (int ni = 0; ni < 4; ++ni) gacc[mi][ni] = (f4v){0.f, 0.f, 0.f, 0.f};
    #pragma unroll
    for (int ni = 0; ni < 4; ++ni) {
        #pragma unroll
        for (int kt = 0; kt < 2; ++kt) {
            size_t off = wb + (size_t)(ni * 16 + m16) * 64 + kt * 32 + quad * 8;
            s8v bh = *(const s8v*)(wgh + off);
            s8v bl = *(const s8v*)(wgl + off);
            #pragma unroll
            for (int mi = 0; mi < 2; ++mi) {
                gacc[mi][ni] = __builtin_amdgcn_mfma_f32_16x16x32_bf16(c_h[mi][kt], bh, gacc[mi][ni], 0, 0, 0);
                gacc[mi][ni] = __builtin_amdgcn_mfma_f32_16x16x32_bf16(c_l[mi][kt], bh, gacc[mi][ni], 0, 0, 0);
                gacc[mi][ni] = __builtin_amdgcn_mfma_f32_16x16x32_bf16(c_h[mi][kt], bl, gacc[mi][ni], 0, 0, 0);
            }
        }
    }

    // ---- s = x*Wsk + bsk + sigm(g)*h2
    {
        float bgd[4], wskd[4], bskd[4];
        #pragma unroll
        for (int ni = 0; ni < 4; ++ni) {
            int d = v * 64 + ni * 16 + m16;
            bgd[ni] = bg[d]; wskd[ni] = Wsk[d]; bskd[ni] = bsk[d];
        }
        float xtok[2][4];
        #pragma unroll
        for (int mi = 0; mi < 2; ++mi)
            #pragma unroll
            for (int r = 0; r < 4; ++r) xtok[mi][r] = xs[wave][mi * 16 + quad * 4 + r];
        #pragma unroll
        for (int mi = 0; mi < 2; ++mi)
            #pragma unroll
            for (int ni = 0; ni < 4; ++ni)
                #pragma unroll
                for (int r = 0; r < 4; ++r) {
                    float g = sigm_f(gacc[mi][ni][r] + bgd[ni]);
                    gacc[mi][ni][r] = fmaf(xtok[mi][r], wskd[ni], bskd[ni]) + g * hacc[mi][ni][r];
                }
    }

    // ---- LayerNorm over d (16-lane shuffle) + bf16 store
    {
        float gamd[4], betd[4];
        #pragma unroll
        for (int ni = 0; ni < 4; ++ni) {
            int d = v * 64 + ni * 16 + m16;
            gamd[ni] = gamma[d]; betd[ni] = beta[d];
        }
        #pragma unroll
        for (int mi = 0; mi < 2; ++mi)
            #pragma unroll
            for (int r = 0; r < 4; ++r) {
                float s0 = gacc[mi][0][r], s1 = gacc[mi][1][r], s2 = gacc[mi][2][r], s3 = gacc[mi][3][r];
                float sum = s0 + s1 + s2 + s3;
                float sq  = s0 * s0 + s1 * s1 + s2 * s2 + s3 * s3;
                #pragma unroll
                for (int m = 1; m < 16; m <<= 1) { sum += __shfl_xor(sum, m); sq += __shfl_xor(sq, m); }
                float mu  = sum * 0.015625f;
                float var = sq * 0.015625f - mu * mu;
                float rs  = rsqrtf(var + LN_EPS);
                size_t base = (size_t)(tile0 + mi * 16 + quad * 4 + r) * 4096 + (size_t)v * 64 + m16;
                #pragma unroll
                for (int ni = 0; ni < 4; ++ni)
                    stb[base + ni * 16] = __float2bfloat16(
                        (gacc[mi][ni][r] - mu) * rs * gamd[ni] + betd[ni]);
            }
    }
}

// ---------------- Stage 2a: part[s][tok][0:128] = flat @ [Wn1|Wns] over K-range s
__global__ __launch_bounds__(256) void vsn_stage2a(
    const __hip_bfloat16* __restrict__ stb,   // [8192][4096]
    const __hip_bfloat16* __restrict__ wct,   // [128][4096]
    float* __restrict__ part)
{
    const int t = threadIdx.x;
    const int wave = t >> 6, lane = t & 63;
    const int tok0 = blockIdx.x * 64;
    const int s = blockIdx.y;
    const int k0 = s * KRANGE;
    const int m16 = lane & 15, quad = lane >> 4;
    const int n0 = wave * 32;

    const short* A  = (const short*)stb;
    const short* Bw = (const short*)wct;

    f4v acc[4][2];
    #pragma unroll
    for (int i = 0; i < 4; ++i)
        #pragma unroll
        for (int j = 0; j < 2; ++j)
            acc[i][j] = (f4v){0.f, 0.f, 0.f, 0.f};

    const short* arow = A  + (size_t)(tok0 + m16) * 4096 + quad * 8;
    const short* brow = Bw + (size_t)(n0 + m16) * 4096 + quad * 8;

    for (int k = k0; k < k0 + KRANGE; k += 32) {
        s8v a[4], b[2];
        #pragma unroll
        for (int i = 0; i < 4; ++i)
            a[i] = *(const s8v*)(arow + (size_t)i * 16 * 4096 + k);
        #pragma unroll
        for (int j = 0; j < 2; ++j)
            b[j] = *(const s8v*)(brow + (size_t)j * 16 * 4096 + k);
        #pragma unroll
        for (int i = 0; i < 4; ++i)
            #pragma unroll
            for (int j = 0; j < 2; ++j)
                acc[i][j] = __builtin_amdgcn_mfma_f32_16x16x32_bf16(a[i], b[j], acc[i][j], 0, 0, 0);
    }

    #pragma unroll
    for (int i = 0; i < 4; ++i)
        #pragma unroll
        for (int j = 0; j < 2; ++j)
            #pragma unroll
            for (int r = 0; r < 4; ++r)
                part[((size_t)s * NTOK + tok0 + i * 16 + quad * 4 + r) * 128
                     + n0 + j * 16 + m16] = acc[i][j][r];
}

// ---------------- Stage 2b: reduce partials, tail GRN, softmax, vectorized weighted sum
// 8 tokens per block -> 1024 blocks, 256 threads.
__global__ __launch_bounds__(256) void vsn_stage2b(
    const __hip_bfloat16* __restrict__ stb, const float* __restrict__ part,
    const float* __restrict__ bn1,
    const float* __restrict__ Wn2, const float* __restrict__ bn2,
    const float* __restrict__ Wng, const float* __restrict__ bng,
    const float* __restrict__ bns,
    const float* __restrict__ ngamma, const float* __restrict__ nbeta,
    float* __restrict__ out)
{
    const int t = threadIdx.x;
    const int tok0 = blockIdx.x * 8;

    __shared__ __align__(16) float hw1_s[8][64];
    __shared__ float skw_s[8][64];
    __shared__ __align__(16) float hw2_s[8][64];
    __shared__ float s2_s[8][64];
    __shared__ float w_s[8][64];

    // ---- reduce K-split partials: hw1 = elu(.+bn1), skw = .+bns
    #pragma unroll
    for (int i = 0; i < 2; ++i) {
        int oidx = i * 256 + t;
        int tt = oidx >> 6, jj = oidx & 63;
        size_t rb = (size_t)(tok0 + tt) * 128;
        float p1 = 0.f, ps = 0.f;
        #pragma unroll
        for (int s = 0; s < KSPLIT; ++s) {
            p1 += part[(size_t)s * NTOK * 128 + rb + jj];
            ps += part[(size_t)s * NTOK * 128 + rb + 64 + jj];
        }
        hw1_s[tt][jj] = elu_f(p1 + bn1[jj]);
        skw_s[tt][jj] = ps + bns[jj];
    }
    __syncthreads();

    // ---- hw2 = hw1 @ Wn2 + bn2
    #pragma unroll
    for (int i = 0; i < 2; ++i) {
        int oidx = i * 256 + t;
        int tt = oidx >> 6, jj = oidx & 63;
        float acc = bn2[jj];
        #pragma unroll
        for (int k4 = 0; k4 < 16; ++k4) {
            float4 h = *(const float4*)&hw1_s[tt][k4 * 4];
            acc += h.x * Wn2[(k4*4+0)*64+jj] + h.y * Wn2[(k4*4+1)*64+jj]
                 + h.z * Wn2[(k4*4+2)*64+jj] + h.w * Wn2[(k4*4+3)*64+jj];
        }
        hw2_s[tt][jj] = acc;
    }
    __syncthreads();

    // ---- gw = sigmoid(hw2 @ Wng + bng); s2 = skw + gw*hw2
    #pragma unroll
    for (int i = 0; i < 2; ++i) {
        int oidx = i * 256 + t;
        int tt = oidx >> 6, vv = oidx & 63;
        float acc = bng[vv];
        #pragma unroll
        for (int k4 = 0; k4 < 16; ++k4) {
            float4 h = *(const float4*)&hw2_s[tt][k4 * 4];
            acc += h.x * Wng[(k4*4+0)*64+vv] + h.y * Wng[(k4*4+1)*64+vv]
                 + h.z * Wng[(k4*4+2)*64+vv] + h.w * Wng[(k4*4+3)*64+vv];
        }
        float gw = sigm_f(acc);
        s2_s[tt][vv] = skw_s[tt][vv] + gw * hw2_s[tt][vv];
    }
    __syncthreads();

    // ---- LN over v + softmax; 16 lanes per token (tokens 0..7 -> threads 0..127)
    if (t < 128) {
        int tt = t >> 4, l = t & 15;
        float z[4]; float sum = 0.f, sq = 0.f;
        #pragma unroll
        for (int i = 0; i < 4; ++i) { z[i] = s2_s[tt][l + 16 * i]; sum += z[i]; sq += z[i] * z[i]; }
        #pragma unroll
        for (int m = 1; m < 16; m <<= 1) { sum += __shfl_xor(sum, m); sq += __shfl_xor(sq, m); }
        float mu  = sum * 0.015625f;
        float var = sq * 0.015625f - mu * mu;
        float rs  = rsqrtf(var + LN_EPS);
        float ln[4]; float mx = -1e30f;
        #pragma unroll
        for (int i = 0; i < 4; ++i) {
            ln[i] = (z[i] - mu) * rs * ngamma[l + 16 * i] + nbeta[l + 16 * i];
            mx = fmaxf(mx, ln[i]);
        }
        #pragma unroll
        for (int m = 1; m < 16; m <<= 1) mx = fmaxf(mx, __shfl_xor(mx, m));
        float es = 0.f; float ev[4];
        #pragma unroll
        for (int i = 0; i < 4; ++i) { ev[i] = __expf(ln[i] - mx); es += ev[i]; }
        #pragma unroll
        for (int m = 1; m < 16; m <<= 1) es += __shfl_xor(es, m);
        float inv = 1.f / es;
        #pragma unroll
        for (int i = 0; i < 4; ++i) w_s[tt][l + 16 * i] = ev[i] * inv;
    }
    __syncthreads();

    // ---- weighted sum, vectorized: wave wv handles tokens {2wv, 2wv+1}.
    // lane: vloc = lane>>3 (v-slice), d8 = (lane&7)*8. Each iter: 16B load = 8 d's.
    {
        const int lane = t & 63, wv = t >> 6;
        const int vloc = lane >> 3, d8 = (lane & 7) * 8;
        const short* s0 = (const short*)stb + (size_t)(tok0 + wv * 2) * 4096 + d8;
        const short* s1 = s0 + 4096;
        float acc0[8], acc1[8];
        #pragma unroll
        for (int j = 0; j < 8; ++j) { acc0[j] = 0.f; acc1[j] = 0.f; }
        #pragma unroll
        for (int vc = 0; vc < 8; ++vc) {
            int v = vc * 8 + vloc;
            s8v r0 = *(const s8v*)(s0 + v * 64);
            s8v r1 = *(const s8v*)(s1 + v * 64);
            float w0 = w_s[wv * 2][v], w1 = w_s[wv * 2 + 1][v];
            #pragma unroll
            for (int j = 0; j < 8; ++j) {
                acc0[j] = fmaf(w0, bf16_to_f((unsigned short)r0[j]), acc0[j]);
                acc1[j] = fmaf(w1, bf16_to_f((unsigned short)r1[j]), acc1[j]);
            }
        }
        #pragma unroll
        for (int m = 8; m <= 32; m <<= 1)
            #pragma unroll
            for (int j = 0; j < 8; ++j) {
                acc0[j] += __shfl_xor(acc0[j], m);
                acc1[j] += __shfl_xor(acc1[j], m);
            }
        if (lane < 8) {
            float* op = out + (size_t)(tok0 + wv * 2) * 64 + lane * 8;
            *(float4*)op       = make_float4(acc0[0], acc0[1], acc0[2], acc0[3]);
            *(float4*)(op + 4) = make_float4(acc0[4], acc0[5], acc0[6], acc0[7]);
            op += 64;
            *(float4*)op       = make_float4(acc1[0], acc1[1], acc1[2], acc1[3]);
            *(float4*)(op + 4) = make_float4(acc1[4], acc1[5], acc1[6], acc1[7]);
        }
    }
}

extern "C" void kernel_launch(void* const* d_in, const int* in_sizes, int n_in,
                              void* d_out, int out_size, void* d_ws, size_t ws_size,
                              hipStream_t stream) {
    const float* x     = (const float*)d_in[0];
    const float* W1    = (const float*)d_in[1];
    const float* b1    = (const float*)d_in[2];
    const float* W2    = (const float*)d_in[3];
    const float* b2    = (const float*)d_in[4];
    const float* Wg    = (const float*)d_in[5];
    const float* bg    = (const float*)d_in[6];
    const float* Wsk   = (const float*)d_in[7];
    const float* bsk   = (const float*)d_in[8];
    const float* gamma = (const float*)d_in[9];
    const float* beta  = (const float*)d_in[10];
    const float* Wn1   = (const float*)d_in[11];
    const float* bn1   = (const float*)d_in[12];
    const float* Wn2   = (const float*)d_in[13];
    const float* bn2   = (const float*)d_in[14];
    const float* Wng   = (const float*)d_in[15];
    const float* bng   = (const float*)d_in[16];
    const float* Wns   = (const float*)d_in[17];
    const float* bns   = (const float*)d_in[18];
    const float* ngam  = (const float*)d_in[19];
    const float* nbet  = (const float*)d_in[20];

    char* ws = (char*)d_ws;
    __hip_bfloat16* stb = (__hip_bfloat16*)ws;                       // 64 MiB
    __hip_bfloat16* wct = (__hip_bfloat16*)(ws + (64u << 20));       // 1 MiB
    float* part = (float*)(ws + (65u << 20));                        // 32 MiB
    short* w2h = (short*)(ws + (97u << 20));                         // 512 KiB each
    short* w2l = w2h + 262144;
    short* wgh = w2l + 262144;
    short* wgl = wgh + 262144;
    float* outp = (float*)d_out;

    vsn_prepack<<<dim3(1024 + 2048), 256, 0, stream>>>(
        W2, Wg, w2h, w2l, wgh, wgl, Wn1, Wns, wct);
    vsn_stage1<<<dim3(NTOK / 32, 16), 256, 0, stream>>>(
        x, W1, b1, w2h, w2l, wgh, wgl, b2, bg, Wsk, bsk, gamma, beta, stb);
    vsn_stage2a<<<dim3(NTOK / 64, KSPLIT), 256, 0, stream>>>(stb, wct, part);
    vsn_stage2b<<<dim3(NTOK / 8), 256, 0, stream>>>(
        stb, part, bn1, Wn2, bn2, Wng, bng, bns, ngam, nbet, outp);
}

// Round 6
// 233.683 us; speedup vs baseline: 5.5419x; 1.1346x over previous
//
#include <hip/hip_runtime.h>
#include <hip/hip_bf16.h>
#include <math.h>

#define NV 64
#define ND 64
#define NTOK 8192
#define LN_EPS 1e-5f
#define KSPLIT 16
#define KRANGE (4096 / KSPLIT)   // 256

typedef __attribute__((ext_vector_type(8))) short s8v;    // 8 bf16 = 4 VGPR
typedef __attribute__((ext_vector_type(4))) float f4v;    // MFMA C/D

__device__ __forceinline__ float sigm_f(float x) { return 1.f / (1.f + __expf(-x)); }
__device__ __forceinline__ float elu_f(float x)  { return x > 0.f ? x : (__expf(x) - 1.f); }

__device__ __forceinline__ float bf16_to_f(unsigned short s) {
    union { unsigned int u; float f; } c; c.u = ((unsigned int)s) << 16;
    return c.f;
}
__device__ __forceinline__ unsigned short bf16_rne(float f) {
    union { float f; unsigned int u; } c; c.f = f;
    return (unsigned short)((c.u + 0x7fffu + ((c.u >> 16) & 1u)) >> 16);
}

// ---------------- Prepack: RNE-bf16 transposed weight planes, coalesced writes
// b < 1024:  w2b/wgb[v][e][d] <- W2/Wg[v][d][e]   (strided reads, coalesced writes)
// b >= 1024: wct[n][k] = concat(Wn1,Wns)[k][n]
__global__ __launch_bounds__(256) void vsn_prepack(
    const float* __restrict__ W2, const float* __restrict__ Wg,
    short* __restrict__ w2b, short* __restrict__ wgb,
    const float* __restrict__ Wn1, const float* __restrict__ Wns,
    __hip_bfloat16* __restrict__ wct)
{
    int b = blockIdx.x;
    if (b < 1024) {
        int idx = b * 256 + threadIdx.x;          // ordered as [v][e][d]
        int v = idx >> 12, e = (idx >> 6) & 63, d = idx & 63;
        size_t src = (size_t)v * 4096 + d * 64 + e;
        w2b[idx] = (short)bf16_rne(W2[src]);
        wgb[idx] = (short)bf16_rne(Wg[src]);
    } else {
        int idx = (b - 1024) * 256 + threadIdx.x;   // 524288
        int n = idx >> 12, k = idx & 4095;
        float v = (n < 64) ? Wn1[(size_t)k * 64 + n] : Wns[(size_t)k * 64 + (n - 64)];
        wct[idx] = __float2bfloat16(v);
    }
}

// ---------------- Stage 1: per-variable GRN + LN via plain-bf16 MFMA -> stacked bf16
// wave = one variable x 32 tokens; grid (256 token-tiles, 16 var-groups), block 256.
__global__ __launch_bounds__(256) void vsn_stage1(
    const float* __restrict__ x,
    const float* __restrict__ W1, const float* __restrict__ b1,
    const short* __restrict__ w2b, const short* __restrict__ wgb,
    const float* __restrict__ b2, const float* __restrict__ bg,
    const float* __restrict__ Wsk, const float* __restrict__ bsk,
    const float* __restrict__ gamma, const float* __restrict__ beta,
    __hip_bfloat16* __restrict__ stb)
{
    const int t = threadIdx.x;
    const int wave = t >> 6, lane = t & 63;
    const int m16 = lane & 15, quad = lane >> 4;
    const int tile0 = blockIdx.x * 32;
    const int v = blockIdx.y * 4 + wave;

    __shared__ float xs[4][32];
    __shared__ __align__(16) unsigned short h2s[4][32][72];  // bf16 h2, per-wave

    if (lane < 32) xs[wave][lane] = x[(size_t)(tile0 + lane) * NV + v];
    // same-wave LDS RAW below: compiler inserts lgkmcnt; no barrier needed.

    // ---- h1 fragments: A[m=lane&15][k=quad*8+j], RNE bf16
    s8v a[2][2];
    #pragma unroll
    for (int kt = 0; kt < 2; ++kt) {
        float w1k[8], b1k[8];
        *(float4*)&w1k[0] = *(const float4*)(W1 + v * 64 + kt * 32 + quad * 8);
        *(float4*)&w1k[4] = *(const float4*)(W1 + v * 64 + kt * 32 + quad * 8 + 4);
        *(float4*)&b1k[0] = *(const float4*)(b1 + v * 64 + kt * 32 + quad * 8);
        *(float4*)&b1k[4] = *(const float4*)(b1 + v * 64 + kt * 32 + quad * 8 + 4);
        #pragma unroll
        for (int mi = 0; mi < 2; ++mi) {
            float xv = xs[wave][mi * 16 + m16];
            #pragma unroll
            for (int j = 0; j < 8; ++j)
                a[mi][kt][j] = (short)bf16_rne(elu_f(fmaf(xv, w1k[j], b1k[j])));
        }
    }

    // ---- GEMM1: h2 = h1 @ W2_v + b2
    f4v hacc[2][4];
    #pragma unroll
    for (int mi = 0; mi < 2; ++mi)
        #pragma unroll
        for (int ni = 0; ni < 4; ++ni) hacc[mi][ni] = (f4v){0.f, 0.f, 0.f, 0.f};

    const size_t wb = (size_t)v * 4096;
    #pragma unroll
    for (int ni = 0; ni < 4; ++ni)
        #pragma unroll
        for (int kt = 0; kt < 2; ++kt) {
            s8v bh = *(const s8v*)(w2b + wb + (size_t)(ni * 16 + m16) * 64 + kt * 32 + quad * 8);
            #pragma unroll
            for (int mi = 0; mi < 2; ++mi)
                hacc[mi][ni] = __builtin_amdgcn_mfma_f32_16x16x32_bf16(a[mi][kt], bh, hacc[mi][ni], 0, 0, 0);
        }
    {
        float b2d[4];
        #pragma unroll
        for (int ni = 0; ni < 4; ++ni) b2d[ni] = b2[v * 64 + ni * 16 + m16];
        #pragma unroll
        for (int mi = 0; mi < 2; ++mi)
            #pragma unroll
            for (int ni = 0; ni < 4; ++ni)
                #pragma unroll
                for (int r = 0; r < 4; ++r) hacc[mi][ni][r] += b2d[ni];
    }

    // ---- h2: C-layout -> LDS (bf16 u16) -> A-layout fragments (same-wave RAW)
    #pragma unroll
    for (int mi = 0; mi < 2; ++mi)
        #pragma unroll
        for (int ni = 0; ni < 4; ++ni)
            #pragma unroll
            for (int r = 0; r < 4; ++r)
                h2s[wave][mi * 16 + quad * 4 + r][ni * 16 + m16] = bf16_rne(hacc[mi][ni][r]);

    s8v c[2][2];
    #pragma unroll
    for (int mi = 0; mi < 2; ++mi)
        #pragma unroll
        for (int kt = 0; kt < 2; ++kt)
            c[mi][kt] = *(const s8v*)&h2s[wave][mi * 16 + m16][kt * 32 + quad * 8];

    // ---- GEMM2: g = sigmoid(h2 @ Wg_v + bg)
    f4v gacc[2][4];
    #pragma unroll
    for (int mi = 0; mi < 2; ++mi)
        #pragma unroll
        for (int ni = 0; ni < 4; ++ni) gacc[mi][ni] = (f4v){0.f, 0.f, 0.f, 0.f};
    #pragma unroll
    for (int ni = 0; ni < 4; ++ni)
        #pragma unroll
        for (int kt = 0; kt < 2; ++kt) {
            s8v bh = *(const s8v*)(wgb + wb + (size_t)(ni * 16 + m16) * 64 + kt * 32 + quad * 8);
            #pragma unroll
            for (int mi = 0; mi < 2; ++mi)
                gacc[mi][ni] = __builtin_amdgcn_mfma_f32_16x16x32_bf16(c[mi][kt], bh, gacc[mi][ni], 0, 0, 0);
        }

    // ---- s = x*Wsk + bsk + sigm(g)*h2
    {
        float bgd[4], wskd[4], bskd[4];
        #pragma unroll
        for (int ni = 0; ni < 4; ++ni) {
            int d = v * 64 + ni * 16 + m16;
            bgd[ni] = bg[d]; wskd[ni] = Wsk[d]; bskd[ni] = bsk[d];
        }
        float xtok[2][4];
        #pragma unroll
        for (int mi = 0; mi < 2; ++mi)
            #pragma unroll
            for (int r = 0; r < 4; ++r) xtok[mi][r] = xs[wave][mi * 16 + quad * 4 + r];
        #pragma unroll
        for (int mi = 0; mi < 2; ++mi)
            #pragma unroll
            for (int ni = 0; ni < 4; ++ni)
                #pragma unroll
                for (int r = 0; r < 4; ++r) {
                    float g = sigm_f(gacc[mi][ni][r] + bgd[ni]);
                    gacc[mi][ni][r] = fmaf(xtok[mi][r], wskd[ni], bskd[ni]) + g * hacc[mi][ni][r];
                }
    }

    // ---- LayerNorm over d (16-lane shuffle) + bf16 store
    {
        float gamd[4], betd[4];
        #pragma unroll
        for (int ni = 0; ni < 4; ++ni) {
            int d = v * 64 + ni * 16 + m16;
            gamd[ni] = gamma[d]; betd[ni] = beta[d];
        }
        #pragma unroll
        for (int mi = 0; mi < 2; ++mi)
            #pragma unroll
            for (int r = 0; r < 4; ++r) {
                float s0 = gacc[mi][0][r], s1 = gacc[mi][1][r], s2 = gacc[mi][2][r], s3 = gacc[mi][3][r];
                float sum = s0 + s1 + s2 + s3;
                float sq  = s0 * s0 + s1 * s1 + s2 * s2 + s3 * s3;
                #pragma unroll
                for (int m = 1; m < 16; m <<= 1) { sum += __shfl_xor(sum, m); sq += __shfl_xor(sq, m); }
                float mu  = sum * 0.015625f;
                float var = sq * 0.015625f - mu * mu;
                float rs  = rsqrtf(var + LN_EPS);
                size_t base = (size_t)(tile0 + mi * 16 + quad * 4 + r) * 4096 + (size_t)v * 64 + m16;
                #pragma unroll
                for (int ni = 0; ni < 4; ++ni)
                    stb[base + ni * 16] = __float2bfloat16(
                        (gacc[mi][ni][r] - mu) * rs * gamd[ni] + betd[ni]);
            }
    }
}

// ---------------- Stage 2a: part[s][tok][0:128] = flat @ [Wn1|Wns] over K-range s
// grid (128 M-tiles, 16 K-splits), block 256 (4 waves), no LDS.
__global__ __launch_bounds__(256) void vsn_stage2a(
    const __hip_bfloat16* __restrict__ stb,   // [8192][4096]
    const __hip_bfloat16* __restrict__ wct,   // [128][4096]
    float* __restrict__ part)
{
    const int t = threadIdx.x;
    const int wave = t >> 6, lane = t & 63;
    const int tok0 = blockIdx.x * 64;
    const int s = blockIdx.y;
    const int k0 = s * KRANGE;
    const int m16 = lane & 15, quad = lane >> 4;
    const int n0 = wave * 32;

    const short* A  = (const short*)stb;
    const short* Bw = (const short*)wct;

    f4v acc[4][2];
    #pragma unroll
    for (int i = 0; i < 4; ++i)
        #pragma unroll
        for (int j = 0; j < 2; ++j)
            acc[i][j] = (f4v){0.f, 0.f, 0.f, 0.f};

    const short* arow = A  + (size_t)(tok0 + m16) * 4096 + quad * 8;
    const short* brow = Bw + (size_t)(n0 + m16) * 4096 + quad * 8;

    for (int k = k0; k < k0 + KRANGE; k += 32) {
        s8v a[4], b[2];
        #pragma unroll
        for (int i = 0; i < 4; ++i)
            a[i] = *(const s8v*)(arow + (size_t)i * 16 * 4096 + k);
        #pragma unroll
        for (int j = 0; j < 2; ++j)
            b[j] = *(const s8v*)(brow + (size_t)j * 16 * 4096 + k);
        #pragma unroll
        for (int i = 0; i < 4; ++i)
            #pragma unroll
            for (int j = 0; j < 2; ++j)
                acc[i][j] = __builtin_amdgcn_mfma_f32_16x16x32_bf16(a[i], b[j], acc[i][j], 0, 0, 0);
    }

    #pragma unroll
    for (int i = 0; i < 4; ++i)
        #pragma unroll
        for (int j = 0; j < 2; ++j)
            #pragma unroll
            for (int r = 0; r < 4; ++r)
                part[((size_t)s * NTOK + tok0 + i * 16 + quad * 4 + r) * 128
                     + n0 + j * 16 + m16] = acc[i][j][r];
}

// ---------------- Stage 2b: reduce partials, tail GRN, softmax, vectorized weighted sum
// 8 tokens per block -> 1024 blocks, 256 threads.
__global__ __launch_bounds__(256) void vsn_stage2b(
    const __hip_bfloat16* __restrict__ stb, const float* __restrict__ part,
    const float* __restrict__ bn1,
    const float* __restrict__ Wn2, const float* __restrict__ bn2,
    const float* __restrict__ Wng, const float* __restrict__ bng,
    const float* __restrict__ bns,
    const float* __restrict__ ngamma, const float* __restrict__ nbeta,
    float* __restrict__ out)
{
    const int t = threadIdx.x;
    const int tok0 = blockIdx.x * 8;

    __shared__ __align__(16) float hw1_s[8][64];
    __shared__ float skw_s[8][64];
    __shared__ __align__(16) float hw2_s[8][64];
    __shared__ float s2_s[8][64];
    __shared__ float w_s[8][64];

    // ---- reduce K-split partials: hw1 = elu(.+bn1), skw = .+bns
    #pragma unroll
    for (int i = 0; i < 2; ++i) {
        int oidx = i * 256 + t;
        int tt = oidx >> 6, jj = oidx & 63;
        size_t rb = (size_t)(tok0 + tt) * 128;
        float p1 = 0.f, ps = 0.f;
        #pragma unroll
        for (int s = 0; s < KSPLIT; ++s) {
            p1 += part[(size_t)s * NTOK * 128 + rb + jj];
            ps += part[(size_t)s * NTOK * 128 + rb + 64 + jj];
        }
        hw1_s[tt][jj] = elu_f(p1 + bn1[jj]);
        skw_s[tt][jj] = ps + bns[jj];
    }
    __syncthreads();

    // ---- hw2 = hw1 @ Wn2 + bn2
    #pragma unroll
    for (int i = 0; i < 2; ++i) {
        int oidx = i * 256 + t;
        int tt = oidx >> 6, jj = oidx & 63;
        float acc = bn2[jj];
        #pragma unroll
        for (int k4 = 0; k4 < 16; ++k4) {
            float4 h = *(const float4*)&hw1_s[tt][k4 * 4];
            acc += h.x * Wn2[(k4*4+0)*64+jj] + h.y * Wn2[(k4*4+1)*64+jj]
                 + h.z * Wn2[(k4*4+2)*64+jj] + h.w * Wn2[(k4*4+3)*64+jj];
        }
        hw2_s[tt][jj] = acc;
    }
    __syncthreads();

    // ---- gw = sigmoid(hw2 @ Wng + bng); s2 = skw + gw*hw2
    #pragma unroll
    for (int i = 0; i < 2; ++i) {
        int oidx = i * 256 + t;
        int tt = oidx >> 6, vv = oidx & 63;
        float acc = bng[vv];
        #pragma unroll
        for (int k4 = 0; k4 < 16; ++k4) {
            float4 h = *(const float4*)&hw2_s[tt][k4 * 4];
            acc += h.x * Wng[(k4*4+0)*64+vv] + h.y * Wng[(k4*4+1)*64+vv]
                 + h.z * Wng[(k4*4+2)*64+vv] + h.w * Wng[(k4*4+3)*64+vv];
        }
        float gw = sigm_f(acc);
        s2_s[tt][vv] = skw_s[tt][vv] + gw * hw2_s[tt][vv];
    }
    __syncthreads();

    // ---- LN over v + softmax; 16 lanes per token (tokens 0..7 -> threads 0..127)
    if (t < 128) {
        int tt = t >> 4, l = t & 15;
        float z[4]; float sum = 0.f, sq = 0.f;
        #pragma unroll
        for (int i = 0; i < 4; ++i) { z[i] = s2_s[tt][l + 16 * i]; sum += z[i]; sq += z[i] * z[i]; }
        #pragma unroll
        for (int m = 1; m < 16; m <<= 1) { sum += __shfl_xor(sum, m); sq += __shfl_xor(sq, m); }
        float mu  = sum * 0.015625f;
        float var = sq * 0.015625f - mu * mu;
        float rs  = rsqrtf(var + LN_EPS);
        float ln[4]; float mx = -1e30f;
        #pragma unroll
        for (int i = 0; i < 4; ++i) {
            ln[i] = (z[i] - mu) * rs * ngamma[l + 16 * i] + nbeta[l + 16 * i];
            mx = fmaxf(mx, ln[i]);
        }
        #pragma unroll
        for (int m = 1; m < 16; m <<= 1) mx = fmaxf(mx, __shfl_xor(mx, m));
        float es = 0.f; float ev[4];
        #pragma unroll
        for (int i = 0; i < 4; ++i) { ev[i] = __expf(ln[i] - mx); es += ev[i]; }
        #pragma unroll
        for (int m = 1; m < 16; m <<= 1) es += __shfl_xor(es, m);
        float inv = 1.f / es;
        #pragma unroll
        for (int i = 0; i < 4; ++i) w_s[tt][l + 16 * i] = ev[i] * inv;
    }
    __syncthreads();

    // ---- weighted sum, vectorized: wave wv handles tokens {2wv, 2wv+1}
    {
        const int lane = t & 63, wv = t >> 6;
        const int vloc = lane >> 3, d8 = (lane & 7) * 8;
        const short* s0 = (const short*)stb + (size_t)(tok0 + wv * 2) * 4096 + d8;
        const short* s1 = s0 + 4096;
        float acc0[8], acc1[8];
        #pragma unroll
        for (int j = 0; j < 8; ++j) { acc0[j] = 0.f; acc1[j] = 0.f; }
        #pragma unroll
        for (int vc = 0; vc < 8; ++vc) {
            int v = vc * 8 + vloc;
            s8v r0 = *(const s8v*)(s0 + v * 64);
            s8v r1 = *(const s8v*)(s1 + v * 64);
            float w0 = w_s[wv * 2][v], w1 = w_s[wv * 2 + 1][v];
            #pragma unroll
            for (int j = 0; j < 8; ++j) {
                acc0[j] = fmaf(w0, bf16_to_f((unsigned short)r0[j]), acc0[j]);
                acc1[j] = fmaf(w1, bf16_to_f((unsigned short)r1[j]), acc1[j]);
            }
        }
        #pragma unroll
        for (int m = 8; m <= 32; m <<= 1)
            #pragma unroll
            for (int j = 0; j < 8; ++j) {
                acc0[j] += __shfl_xor(acc0[j], m);
                acc1[j] += __shfl_xor(acc1[j], m);
            }
        if (lane < 8) {
            float* op = out + (size_t)(tok0 + wv * 2) * 64 + lane * 8;
            *(float4*)op       = make_float4(acc0[0], acc0[1], acc0[2], acc0[3]);
            *(float4*)(op + 4) = make_float4(acc0[4], acc0[5], acc0[6], acc0[7]);
            op += 64;
            *(float4*)op       = make_float4(acc1[0], acc1[1], acc1[2], acc1[3]);
            *(float4*)(op + 4) = make_float4(acc1[4], acc1[5], acc1[6], acc1[7]);
        }
    }
}

extern "C" void kernel_launch(void* const* d_in, const int* in_sizes, int n_in,
                              void* d_out, int out_size, void* d_ws, size_t ws_size,
                              hipStream_t stream) {
    const float* x     = (const float*)d_in[0];
    const float* W1    = (const float*)d_in[1];
    const float* b1    = (const float*)d_in[2];
    const float* W2    = (const float*)d_in[3];
    const float* b2    = (const float*)d_in[4];
    const float* Wg    = (const float*)d_in[5];
    const float* bg    = (const float*)d_in[6];
    const float* Wsk   = (const float*)d_in[7];
    const float* bsk   = (const float*)d_in[8];
    const float* gamma = (const float*)d_in[9];
    const float* beta  = (const float*)d_in[10];
    const float* Wn1   = (const float*)d_in[11];
    const float* bn1   = (const float*)d_in[12];
    const float* Wn2   = (const float*)d_in[13];
    const float* bn2   = (const float*)d_in[14];
    const float* Wng   = (const float*)d_in[15];
    const float* bng   = (const float*)d_in[16];
    const float* Wns   = (const float*)d_in[17];
    const float* bns   = (const float*)d_in[18];
    const float* ngam  = (const float*)d_in[19];
    const float* nbet  = (const float*)d_in[20];

    char* ws = (char*)d_ws;
    __hip_bfloat16* stb = (__hip_bfloat16*)ws;                       // 64 MiB
    __hip_bfloat16* wct = (__hip_bfloat16*)(ws + (64u << 20));       // 1 MiB
    float* part = (float*)(ws + (65u << 20));                        // 64 MiB (16 x 8192 x 128)
    short* w2b = (short*)(ws + (129u << 20));                        // 512 KiB each
    short* wgb = w2b + 262144;
    float* outp = (float*)d_out;

    vsn_prepack<<<dim3(1024 + 2048), 256, 0, stream>>>(
        W2, Wg, w2b, wgb, Wn1, Wns, wct);
    vsn_stage1<<<dim3(NTOK / 32, 16), 256, 0, stream>>>(
        x, W1, b1, w2b, wgb, b2, bg, Wsk, bsk, gamma, beta, stb);
    vsn_stage2a<<<dim3(NTOK / 64, KSPLIT), 256, 0, stream>>>(stb, wct, part);
    vsn_stage2b<<<dim3(NTOK / 8), 256, 0, stream>>>(
        stb, part, bn1, Wn2, bn2, Wng, bng, bns, ngam, nbet, outp);
}